// Round 1
// baseline (4426.992 us; speedup 1.0000x reference)
//
#include <hip/hip_runtime.h>
#include <hip/hip_bf16.h>

// GCNEncoder: 2-layer GCN with out-degree normalization.
//   h   = (x @ W1) * deg_inv[row];  out1[dst] += h[src];  h2 = relu(out1 + b1)
//   g   = (h2 @ W2) * deg_inv[row]; out[dst]  += g[src];  out += b2
// N=100000, E=1600000, C: 128 -> 128 -> 64, all fp32.

// ---------------- degree ----------------
__global__ void hist_kernel(const int* __restrict__ src, int E, int* __restrict__ deg) {
    int i = blockIdx.x * blockDim.x + threadIdx.x;
    if (i < E) atomicAdd(&deg[src[i]], 1);
}

__global__ void deginv_kernel(const int* __restrict__ deg, float* __restrict__ deg_inv, int N) {
    int i = blockIdx.x * blockDim.x + threadIdx.x;
    if (i < N) {
        int d = deg[i];
        deg_inv[i] = 1.0f / (float)(d < 1 ? 1 : d);
    }
}

// ---------------- GEMM: C[M x NC] = (A[M x 128] @ W[128 x NC]) * scale[row] ----------------
// 64x64 tile per block, 256 threads, 4x4 register blocking. K = 128 fixed.
template <int NC>
__global__ __launch_bounds__(256) void gemm_scale_kernel(
    const float* __restrict__ A, const float* __restrict__ W,
    const float* __restrict__ scale, float* __restrict__ C, int M)
{
    __shared__ float As[128][65];  // [k][row], +1 pad to break bank conflicts
    __shared__ float Ws[128][64];  // [k][col]

    const int r0 = blockIdx.y * 64;
    const int c0 = blockIdx.x * 64;
    const int t  = threadIdx.x;

    // stage A transposed: 64 rows x 128 k
    for (int idx = t; idx < 64 * 128; idx += 256) {
        int r = idx >> 7, k = idx & 127;
        int rg = r0 + r;
        As[k][r] = (rg < M) ? A[(size_t)rg * 128 + k] : 0.0f;
    }
    // stage W slice: 128 k x 64 cols
    for (int idx = t; idx < 128 * 64; idx += 256) {
        int k = idx >> 6, c = idx & 63;
        Ws[k][c] = W[k * NC + c0 + c];
    }
    __syncthreads();

    const int tr = t >> 4;  // 0..15
    const int tc = t & 15;  // 0..15

    float acc[4][4] = {};
#pragma unroll 4
    for (int k = 0; k < 128; ++k) {
        float4 a = *(const float4*)&As[k][tr * 4];
        float4 b = *(const float4*)&Ws[k][tc * 4];
        float av[4] = {a.x, a.y, a.z, a.w};
        float bv[4] = {b.x, b.y, b.z, b.w};
#pragma unroll
        for (int i = 0; i < 4; ++i)
#pragma unroll
            for (int j = 0; j < 4; ++j)
                acc[i][j] = fmaf(av[i], bv[j], acc[i][j]);
    }

#pragma unroll
    for (int i = 0; i < 4; ++i) {
        int rg = r0 + tr * 4 + i;
        if (rg >= M) break;  // thread's rows are consecutive
        float s = scale[rg];
#pragma unroll
        for (int j = 0; j < 4; ++j)
            C[(size_t)rg * NC + c0 + tc * 4 + j] = acc[i][j] * s;
    }
}

// ---------------- scatter-add: out[dst[e]*C + c] += val[src[e]*C + c] ----------------
template <int C>
__global__ void scatter_kernel(const int* __restrict__ src, const int* __restrict__ dst,
                               const float* __restrict__ val, float* __restrict__ out, int E)
{
    constexpr int VEC = C / 4;  // float4 lanes per edge
    int tid = blockIdx.x * blockDim.x + threadIdx.x;
    if (tid >= E * VEC) return;
    int e = tid / VEC;
    int c = (tid & (VEC - 1)) * 4;
    int s = src[e], d = dst[e];
    float4 v = *(const float4*)&val[(size_t)s * C + c];
    float* o = &out[(size_t)d * C + c];
    atomicAdd(o + 0, v.x);
    atomicAdd(o + 1, v.y);
    atomicAdd(o + 2, v.z);
    atomicAdd(o + 3, v.w);
}

// ---------------- bias + relu (in place, C=128) ----------------
__global__ void bias_relu_kernel(float4* __restrict__ h, const float* __restrict__ b, int n4) {
    int i = blockIdx.x * blockDim.x + threadIdx.x;
    if (i >= n4) return;
    int c = (i & 31) << 2;  // 128 cols / 4
    float4 v = h[i];
    v.x = fmaxf(v.x + b[c + 0], 0.0f);
    v.y = fmaxf(v.y + b[c + 1], 0.0f);
    v.z = fmaxf(v.z + b[c + 2], 0.0f);
    v.w = fmaxf(v.w + b[c + 3], 0.0f);
    h[i] = v;
}

// ---------------- init out = b2 broadcast (C=64) ----------------
__global__ void init_out_kernel(float4* __restrict__ out, const float* __restrict__ b, int n4) {
    int i = blockIdx.x * blockDim.x + threadIdx.x;
    if (i >= n4) return;
    int c = (i & 15) << 2;  // 64 cols / 4
    float4 v;
    v.x = b[c + 0]; v.y = b[c + 1]; v.z = b[c + 2]; v.w = b[c + 3];
    out[i] = v;
}

extern "C" void kernel_launch(void* const* d_in, const int* in_sizes, int n_in,
                              void* d_out, int out_size, void* d_ws, size_t ws_size,
                              hipStream_t stream) {
    const float* x  = (const float*)d_in[0];
    const int*   ei = (const int*)d_in[1];
    const float* W1 = (const float*)d_in[2];
    const float* b1 = (const float*)d_in[3];
    const float* W2 = (const float*)d_in[4];
    const float* b2 = (const float*)d_in[5];
    float* out = (float*)d_out;

    const int N = in_sizes[0] / 128;
    const int E = in_sizes[1] / 2;
    const int* src = ei;
    const int* dst = ei + E;

    // workspace layout
    char* ws = (char*)d_ws;
    size_t off = 0;
    auto alloc = [&](size_t bytes) {
        void* p = ws + off;
        off = (off + bytes + 255) & ~(size_t)255;
        return p;
    };
    int*   deg     = (int*)alloc((size_t)N * 4);
    float* deg_inv = (float*)alloc((size_t)N * 4);
    float* h       = (float*)alloc((size_t)N * 128 * 4);
    float* out1    = (float*)alloc((size_t)N * 128 * 4);
    float* g       = h;  // reuse: h is dead after scatter1

    hipMemsetAsync(deg, 0, (size_t)N * 4, stream);
    hipMemsetAsync(out1, 0, (size_t)N * 128 * 4, stream);

    hist_kernel<<<(E + 255) / 256, 256, 0, stream>>>(src, E, deg);
    deginv_kernel<<<(N + 255) / 256, 256, 0, stream>>>(deg, deg_inv, N);

    // layer 1: h = (x @ W1) * deg_inv
    gemm_scale_kernel<128><<<dim3(2, (N + 63) / 64), 256, 0, stream>>>(x, W1, deg_inv, h, N);
    // out1[dst] += h[src]
    {
        int threads = E * 32;  // E * (128/4)
        scatter_kernel<128><<<(threads + 255) / 256, 256, 0, stream>>>(src, dst, h, out1, E);
    }
    // h2 = relu(out1 + b1), in place
    {
        int n4 = N * 32;  // N*128/4
        bias_relu_kernel<<<(n4 + 255) / 256, 256, 0, stream>>>((float4*)out1, b1, n4);
    }
    // layer 2: g = (h2 @ W2) * deg_inv
    gemm_scale_kernel<64><<<dim3(1, (N + 63) / 64), 256, 0, stream>>>(out1, W2, deg_inv, g, N);
    // out = b2; out[dst] += g[src]
    {
        int n4 = N * 16;  // N*64/4
        init_out_kernel<<<(n4 + 255) / 256, 256, 0, stream>>>((float4*)out, b2, n4);
        int threads = E * 16;  // E * (64/4)
        scatter_kernel<64><<<(threads + 255) / 256, 256, 0, stream>>>(src, dst, g, out, E);
    }
}

// Round 2
// 732.993 us; speedup vs baseline: 6.0396x; 6.0396x over previous
//
#include <hip/hip_runtime.h>

// GCNEncoder: 2-layer GCN, out-degree normalization. N=100000, E=1600000,
// C: 128 -> 128 -> 64, fp32.
//
// R2 strategy: replace 205M fp32 atomicAdds (3.2 GB write-through, 2.7 ms)
// with an on-device counting sort by dst (CSR) + one-wave-per-node gather
// aggregation (register accumulate, single write per output row).

#define BLK 256
#define ITEMS 8
#define CHUNK (BLK * ITEMS)  // 2048 elements per scan block

// ---------------- histograms: out-degree (src) + in-degree (dst) ----------------
__global__ void hist2_kernel(const int* __restrict__ src, const int* __restrict__ dst,
                             int E, int* __restrict__ deg_src, int* __restrict__ deg_dst) {
    int i = blockIdx.x * blockDim.x + threadIdx.x;
    if (i < E) {
        atomicAdd(&deg_src[src[i]], 1);
        atomicAdd(&deg_dst[dst[i]], 1);
    }
}

__global__ void deginv_kernel(const int* __restrict__ deg, float* __restrict__ deg_inv, int N) {
    int i = blockIdx.x * blockDim.x + threadIdx.x;
    if (i < N) {
        int d = deg[i];
        deg_inv[i] = 1.0f / (float)(d < 1 ? 1 : d);
    }
}

// ---------------- 2-level exclusive scan of deg_dst -> offsets (and cursor copy) ----------------
__global__ __launch_bounds__(BLK) void scan1_kernel(const int* __restrict__ deg, int* __restrict__ bsum, int N) {
    __shared__ int s[BLK];
    int base = blockIdx.x * CHUNK;
    int t = threadIdx.x;
    int ts = 0;
#pragma unroll
    for (int j = 0; j < ITEMS; ++j) {
        int i = base + t * ITEMS + j;
        if (i < N) ts += deg[i];
    }
    s[t] = ts;
    __syncthreads();
    for (int o = BLK / 2; o > 0; o >>= 1) {
        if (t < o) s[t] += s[t + o];
        __syncthreads();
    }
    if (t == 0) bsum[blockIdx.x] = s[0];
}

__global__ void scan2_kernel(int* __restrict__ bsum, int nb, int* __restrict__ offsets, int N, int E) {
    if (threadIdx.x == 0 && blockIdx.x == 0) {
        int run = 0;
        for (int b = 0; b < nb; ++b) {
            int v = bsum[b];
            bsum[b] = run;
            run += v;
        }
        offsets[N] = E;
    }
}

__global__ __launch_bounds__(BLK) void scan3_kernel(const int* __restrict__ deg, const int* __restrict__ bsum,
                                                    int* __restrict__ offsets, int* __restrict__ cursor, int N) {
    __shared__ int s[BLK];
    int base = blockIdx.x * CHUNK;
    int t = threadIdx.x;
    int v[ITEMS];
    int ts = 0;
#pragma unroll
    for (int j = 0; j < ITEMS; ++j) {
        int i = base + t * ITEMS + j;
        v[j] = (i < N) ? deg[i] : 0;
        ts += v[j];
    }
    s[t] = ts;
    __syncthreads();
    // inclusive Hillis-Steele over 256 thread sums
    for (int o = 1; o < BLK; o <<= 1) {
        int add = (t >= o) ? s[t - o] : 0;
        __syncthreads();
        s[t] += add;
        __syncthreads();
    }
    int run = s[t] - ts + bsum[blockIdx.x];  // exclusive prefix + block offset
#pragma unroll
    for (int j = 0; j < ITEMS; ++j) {
        int i = base + t * ITEMS + j;
        if (i < N) {
            offsets[i] = run;
            cursor[i] = run;
            run += v[j];
        }
    }
}

// ---------------- build sorted_src: counting-sort scatter ----------------
__global__ void build_kernel(const int* __restrict__ src, const int* __restrict__ dst, int E,
                             int* __restrict__ cursor, int* __restrict__ sorted_src) {
    int i = blockIdx.x * blockDim.x + threadIdx.x;
    if (i < E) {
        int pos = atomicAdd(&cursor[dst[i]], 1);
        sorted_src[pos] = src[i];
    }
}

// ---------------- GEMM: C[M x NC] = (A[M x 128] @ W[128 x NC]) * scale[row] ----------------
template <int NC>
__global__ __launch_bounds__(256) void gemm_scale_kernel(
    const float* __restrict__ A, const float* __restrict__ W,
    const float* __restrict__ scale, float* __restrict__ C, int M)
{
    __shared__ float As[128][65];
    __shared__ float Ws[128][64];

    const int r0 = blockIdx.y * 64;
    const int c0 = blockIdx.x * 64;
    const int t  = threadIdx.x;

    for (int idx = t; idx < 64 * 128; idx += 256) {
        int r = idx >> 7, k = idx & 127;
        int rg = r0 + r;
        As[k][r] = (rg < M) ? A[(size_t)rg * 128 + k] : 0.0f;
    }
    for (int idx = t; idx < 128 * 64; idx += 256) {
        int k = idx >> 6, c = idx & 63;
        Ws[k][c] = W[k * NC + c0 + c];
    }
    __syncthreads();

    const int tr = t >> 4;
    const int tc = t & 15;

    float acc[4][4] = {};
#pragma unroll 4
    for (int k = 0; k < 128; ++k) {
        float4 a = *(const float4*)&As[k][tr * 4];
        float4 b = *(const float4*)&Ws[k][tc * 4];
        float av[4] = {a.x, a.y, a.z, a.w};
        float bv[4] = {b.x, b.y, b.z, b.w};
#pragma unroll
        for (int i = 0; i < 4; ++i)
#pragma unroll
            for (int j = 0; j < 4; ++j)
                acc[i][j] = fmaf(av[i], bv[j], acc[i][j]);
    }

#pragma unroll
    for (int i = 0; i < 4; ++i) {
        int rg = r0 + tr * 4 + i;
        if (rg >= M) break;
        float s = scale[rg];
#pragma unroll
        for (int j = 0; j < 4; ++j)
            C[(size_t)rg * NC + c0 + tc * 4 + j] = acc[i][j] * s;
    }
}

// ---------------- aggregation: out[n] = act( sum_{e in csr[n]} val[src[e]] + bias ) ----------------
// One wave (64 lanes) per node. C=128: lane owns 2 cols (float2). C=64: lane owns 1 col.
template <int C, bool RELU>
__global__ __launch_bounds__(256) void aggregate_kernel(
    const int* __restrict__ offsets, const int* __restrict__ sorted_src,
    const float* __restrict__ val, const float* __restrict__ bias,
    float* __restrict__ out, int N)
{
    int node = blockIdx.x * 4 + (threadIdx.x >> 6);
    if (node >= N) return;
    int lane = threadIdx.x & 63;
    int e = offsets[node];
    const int end = offsets[node + 1];

    if (C == 128) {
        float2 acc = {0.0f, 0.0f};
        const int col = lane * 2;
        for (; e + 4 <= end; e += 4) {
            int s0 = sorted_src[e + 0], s1 = sorted_src[e + 1];
            int s2 = sorted_src[e + 2], s3 = sorted_src[e + 3];
            float2 v0 = *(const float2*)&val[(size_t)s0 * 128 + col];
            float2 v1 = *(const float2*)&val[(size_t)s1 * 128 + col];
            float2 v2 = *(const float2*)&val[(size_t)s2 * 128 + col];
            float2 v3 = *(const float2*)&val[(size_t)s3 * 128 + col];
            acc.x += (v0.x + v1.x) + (v2.x + v3.x);
            acc.y += (v0.y + v1.y) + (v2.y + v3.y);
        }
        for (; e < end; ++e) {
            int s = sorted_src[e];
            float2 v = *(const float2*)&val[(size_t)s * 128 + col];
            acc.x += v.x;
            acc.y += v.y;
        }
        float ox = acc.x + bias[col];
        float oy = acc.y + bias[col + 1];
        if (RELU) { ox = fmaxf(ox, 0.0f); oy = fmaxf(oy, 0.0f); }
        *(float2*)&out[(size_t)node * 128 + col] = make_float2(ox, oy);
    } else {
        float acc = 0.0f;
        for (; e + 4 <= end; e += 4) {
            int s0 = sorted_src[e + 0], s1 = sorted_src[e + 1];
            int s2 = sorted_src[e + 2], s3 = sorted_src[e + 3];
            float v0 = val[(size_t)s0 * 64 + lane];
            float v1 = val[(size_t)s1 * 64 + lane];
            float v2 = val[(size_t)s2 * 64 + lane];
            float v3 = val[(size_t)s3 * 64 + lane];
            acc += (v0 + v1) + (v2 + v3);
        }
        for (; e < end; ++e) {
            float v = val[(size_t)sorted_src[e] * 64 + lane];
            acc += v;
        }
        float o = acc + bias[lane];
        if (RELU) o = fmaxf(o, 0.0f);
        out[(size_t)node * 64 + lane] = o;
    }
}

extern "C" void kernel_launch(void* const* d_in, const int* in_sizes, int n_in,
                              void* d_out, int out_size, void* d_ws, size_t ws_size,
                              hipStream_t stream) {
    const float* x  = (const float*)d_in[0];
    const int*   ei = (const int*)d_in[1];
    const float* W1 = (const float*)d_in[2];
    const float* b1 = (const float*)d_in[3];
    const float* W2 = (const float*)d_in[4];
    const float* b2 = (const float*)d_in[5];
    float* out = (float*)d_out;

    const int N = in_sizes[0] / 128;
    const int E = in_sizes[1] / 2;
    const int* src = ei;
    const int* dst = ei + E;

    char* ws = (char*)d_ws;
    size_t off = 0;
    auto alloc = [&](size_t bytes) {
        void* p = ws + off;
        off = (off + bytes + 255) & ~(size_t)255;
        return p;
    };
    int*   deg_src    = (int*)alloc((size_t)N * 4);
    int*   deg_dst    = (int*)alloc((size_t)N * 4);
    float* deg_inv    = (float*)alloc((size_t)N * 4);
    int*   offsets    = (int*)alloc((size_t)(N + 1) * 4);
    int*   cursor     = (int*)alloc((size_t)N * 4);
    int*   bsum       = (int*)alloc((size_t)256 * 4);
    int*   sorted_src = (int*)alloc((size_t)E * 4);
    float* h          = (float*)alloc((size_t)N * 128 * 4);
    float* out1       = (float*)alloc((size_t)N * 128 * 4);
    float* g          = h;  // h is dead after aggregate1

    hipMemsetAsync(deg_src, 0, (size_t)N * 4, stream);
    hipMemsetAsync(deg_dst, 0, (size_t)N * 4, stream);

    hist2_kernel<<<(E + 255) / 256, 256, 0, stream>>>(src, dst, E, deg_src, deg_dst);
    deginv_kernel<<<(N + 255) / 256, 256, 0, stream>>>(deg_src, deg_inv, N);

    const int nb = (N + CHUNK - 1) / CHUNK;
    scan1_kernel<<<nb, BLK, 0, stream>>>(deg_dst, bsum, N);
    scan2_kernel<<<1, 64, 0, stream>>>(bsum, nb, offsets, N, E);
    scan3_kernel<<<nb, BLK, 0, stream>>>(deg_dst, bsum, offsets, cursor, N);
    build_kernel<<<(E + 255) / 256, 256, 0, stream>>>(src, dst, E, cursor, sorted_src);

    // layer 1: h = (x @ W1) * deg_inv ; out1 = relu(Agg(h) + b1)
    gemm_scale_kernel<128><<<dim3(2, (N + 63) / 64), 256, 0, stream>>>(x, W1, deg_inv, h, N);
    aggregate_kernel<128, true><<<(N + 3) / 4, 256, 0, stream>>>(offsets, sorted_src, h, b1, out1, N);

    // layer 2: g = (out1 @ W2) * deg_inv ; out = Agg(g) + b2
    gemm_scale_kernel<64><<<dim3(1, (N + 63) / 64), 256, 0, stream>>>(out1, W2, deg_inv, g, N);
    aggregate_kernel<64, false><<<(N + 3) / 4, 256, 0, stream>>>(offsets, sorted_src, g, b2, out, N);
}

// Round 3
// 530.313 us; speedup vs baseline: 8.3479x; 1.3822x over previous
//
#include <hip/hip_runtime.h>
#include <hip/hip_bf16.h>

// GCNEncoder: 2-layer GCN, out-degree norm. N=100000, E=1600000, 128->128->64, fp32 I/O.
// R3: MFMA bf16 GEMMs (fp32 accum, deg_inv folded into A staging) + bf16 gather payloads.

typedef __attribute__((ext_vector_type(8))) short short8;
typedef __attribute__((ext_vector_type(4))) float floatx4;

__device__ inline unsigned short f2bf(float f) {
    union { float f; unsigned u; } v; v.f = f;
    unsigned r = v.u + 0x7FFF + ((v.u >> 16) & 1);  // round-to-nearest-even
    return (unsigned short)(r >> 16);
}
__device__ inline float bf2f(unsigned short b) {
    union { unsigned u; float f; } v; v.u = ((unsigned)b) << 16;
    return v.f;
}

#define BLK 256
#define ITEMS 8
#define CHUNK (BLK * ITEMS)

// ---------------- degree histograms ----------------
__global__ void hist2_kernel(const int* __restrict__ src, const int* __restrict__ dst,
                             int E, int* __restrict__ deg_src, int* __restrict__ deg_dst) {
    int i = blockIdx.x * blockDim.x + threadIdx.x;
    if (i < E) {
        atomicAdd(&deg_src[src[i]], 1);
        atomicAdd(&deg_dst[dst[i]], 1);
    }
}

__global__ void deginv_kernel(const int* __restrict__ deg, float* __restrict__ deg_inv, int N) {
    int i = blockIdx.x * blockDim.x + threadIdx.x;
    if (i < N) {
        int d = deg[i];
        deg_inv[i] = 1.0f / (float)(d < 1 ? 1 : d);
    }
}

// ---------------- scan (2-level) over deg_dst -> offsets + cursor ----------------
__global__ __launch_bounds__(BLK) void scan1_kernel(const int* __restrict__ deg, int* __restrict__ bsum, int N) {
    __shared__ int s[BLK];
    int base = blockIdx.x * CHUNK;
    int t = threadIdx.x;
    int ts = 0;
#pragma unroll
    for (int j = 0; j < ITEMS; ++j) {
        int i = base + t * ITEMS + j;
        if (i < N) ts += deg[i];
    }
    s[t] = ts;
    __syncthreads();
    for (int o = BLK / 2; o > 0; o >>= 1) {
        if (t < o) s[t] += s[t + o];
        __syncthreads();
    }
    if (t == 0) bsum[blockIdx.x] = s[0];
}

__global__ void scan2_kernel(int* __restrict__ bsum, int nb, int* __restrict__ offsets, int N, int E) {
    if (threadIdx.x == 0 && blockIdx.x == 0) {
        int run = 0;
        for (int b = 0; b < nb; ++b) {
            int v = bsum[b];
            bsum[b] = run;
            run += v;
        }
        offsets[N] = E;
    }
}

__global__ __launch_bounds__(BLK) void scan3_kernel(const int* __restrict__ deg, const int* __restrict__ bsum,
                                                    int* __restrict__ offsets, int* __restrict__ cursor, int N) {
    __shared__ int s[BLK];
    int base = blockIdx.x * CHUNK;
    int t = threadIdx.x;
    int v[ITEMS];
    int ts = 0;
#pragma unroll
    for (int j = 0; j < ITEMS; ++j) {
        int i = base + t * ITEMS + j;
        v[j] = (i < N) ? deg[i] : 0;
        ts += v[j];
    }
    s[t] = ts;
    __syncthreads();
    for (int o = 1; o < BLK; o <<= 1) {
        int add = (t >= o) ? s[t - o] : 0;
        __syncthreads();
        s[t] += add;
        __syncthreads();
    }
    int run = s[t] - ts + bsum[blockIdx.x];
#pragma unroll
    for (int j = 0; j < ITEMS; ++j) {
        int i = base + t * ITEMS + j;
        if (i < N) {
            offsets[i] = run;
            cursor[i] = run;
            run += v[j];
        }
    }
}

__global__ void build_kernel(const int* __restrict__ src, const int* __restrict__ dst, int E,
                             int* __restrict__ cursor, int* __restrict__ sorted_src) {
    int i = blockIdx.x * blockDim.x + threadIdx.x;
    if (i < E) {
        int pos = atomicAdd(&cursor[dst[i]], 1);
        sorted_src[pos] = src[i];
    }
}

// ---------------- MFMA GEMM: Cb[M x NC](bf16) = (A[M x 128] * scale[row]) @ W[128 x NC] ----------------
// Block = 256 thr (4 waves), tile M=128 x full NC, K=128 staged once.
// A dtype: float (AF=1) or bf16-ushort (AF=0). fp32 -> bf16 conversion during staging.
template <int NC, int AF>
__global__ __launch_bounds__(256) void gemm_mfma_kernel(
    const void* __restrict__ Ap, const float* __restrict__ W,
    const float* __restrict__ scale, unsigned short* __restrict__ Cb, int M)
{
    __shared__ unsigned short Al[128][136];  // +8 bf16 pad -> 272 B row stride (breaks bank conflicts)
    __shared__ unsigned short Bl[NC][136];

    const int t = threadIdx.x;
    const int r0 = blockIdx.x * 128;

    // stage A: scaled by deg_inv[row], converted to bf16
    for (int idx = t; idx < 128 * 32; idx += 256) {
        int r = idx >> 5, c4 = (idx & 31) << 2;
        int rg = r0 + r;
        ushort4 w;
        if (rg < M) {
            float s = scale[rg];
            float4 v;
            if (AF) {
                v = *(const float4*)&((const float*)Ap)[(size_t)rg * 128 + c4];
            } else {
                ushort4 u = *(const ushort4*)&((const unsigned short*)Ap)[(size_t)rg * 128 + c4];
                v = make_float4(bf2f(u.x), bf2f(u.y), bf2f(u.z), bf2f(u.w));
            }
            w.x = f2bf(v.x * s); w.y = f2bf(v.y * s);
            w.z = f2bf(v.z * s); w.w = f2bf(v.w * s);
        } else {
            w.x = w.y = w.z = w.w = 0;
        }
        *(ushort4*)&Al[r][c4] = w;
    }
    // stage W transposed: W[k][n] fp32 -> Bl[n][k] bf16 (coalesced global read)
    for (int idx = t; idx < 128 * (NC / 4); idx += 256) {
        int k = idx / (NC / 4), n4 = (idx % (NC / 4)) << 2;
        float4 v = *(const float4*)&W[(size_t)k * NC + n4];
        Bl[n4 + 0][k] = f2bf(v.x);
        Bl[n4 + 1][k] = f2bf(v.y);
        Bl[n4 + 2][k] = f2bf(v.z);
        Bl[n4 + 3][k] = f2bf(v.w);
    }
    __syncthreads();

    constexpr int NT = NC / 16;       // n-tiles per wave
    const int wm = t >> 6;            // wave's 32-row band
    const int lane = t & 63;
    const int lm = lane & 15;
    const int lk = (lane >> 4) * 8;

    floatx4 acc[2][NT];
#pragma unroll
    for (int i = 0; i < 2; ++i)
#pragma unroll
        for (int j = 0; j < NT; ++j) acc[i][j] = (floatx4){0.f, 0.f, 0.f, 0.f};

#pragma unroll
    for (int kk = 0; kk < 4; ++kk) {
        const int kb = kk * 32 + lk;
        short8 af[2];
        af[0] = *(const short8*)&Al[wm * 32 + lm][kb];
        af[1] = *(const short8*)&Al[wm * 32 + 16 + lm][kb];
        short8 bfr[NT];
#pragma unroll
        for (int j = 0; j < NT; ++j)
            bfr[j] = *(const short8*)&Bl[j * 16 + lm][kb];
#pragma unroll
        for (int i = 0; i < 2; ++i)
#pragma unroll
            for (int j = 0; j < NT; ++j)
                acc[i][j] = __builtin_amdgcn_mfma_f32_16x16x32_bf16(af[i], bfr[j], acc[i][j], 0, 0, 0);
    }

    // epilogue: D col = lane&15, row = (lane>>4)*4 + reg  [m89/m91-verified mapping]
    const int rbase = r0 + wm * 32 + (lane >> 4) * 4;
#pragma unroll
    for (int i = 0; i < 2; ++i) {
#pragma unroll
        for (int reg = 0; reg < 4; ++reg) {
            int rg = rbase + i * 16 + reg;
            if (rg < M) {
#pragma unroll
                for (int j = 0; j < NT; ++j)
                    Cb[(size_t)rg * NC + j * 16 + lm] = f2bf(acc[i][j][reg]);
            }
        }
    }
}

// ---------------- aggregate C=128 (bf16 in, bf16 out, +bias, relu): one wave per node ----------------
__global__ __launch_bounds__(256) void aggregate128_kernel(
    const int* __restrict__ offsets, const int* __restrict__ sorted_src,
    const unsigned* __restrict__ val,   // bf16x2, 64 dwords/row
    const float* __restrict__ bias, unsigned* __restrict__ outb, int N)
{
    int node = blockIdx.x * 4 + (threadIdx.x >> 6);
    if (node >= N) return;
    int lane = threadIdx.x & 63;
    int e = offsets[node];
    const int end = offsets[node + 1];
    float ax = 0.f, ay = 0.f;
    for (; e + 4 <= end; e += 4) {
        int s0 = sorted_src[e + 0], s1 = sorted_src[e + 1];
        int s2 = sorted_src[e + 2], s3 = sorted_src[e + 3];
        unsigned v0 = val[(size_t)s0 * 64 + lane];
        unsigned v1 = val[(size_t)s1 * 64 + lane];
        unsigned v2 = val[(size_t)s2 * 64 + lane];
        unsigned v3 = val[(size_t)s3 * 64 + lane];
        ax += (bf2f(v0 & 0xFFFF) + bf2f(v1 & 0xFFFF)) + (bf2f(v2 & 0xFFFF) + bf2f(v3 & 0xFFFF));
        ay += (bf2f(v0 >> 16) + (bf2f(v1 >> 16))) + (bf2f(v2 >> 16) + bf2f(v3 >> 16));
    }
    for (; e < end; ++e) {
        unsigned v = val[(size_t)sorted_src[e] * 64 + lane];
        ax += bf2f(v & 0xFFFF);
        ay += bf2f(v >> 16);
    }
    ax = fmaxf(ax + bias[2 * lane], 0.f);
    ay = fmaxf(ay + bias[2 * lane + 1], 0.f);
    outb[(size_t)node * 64 + lane] = (unsigned)f2bf(ax) | ((unsigned)f2bf(ay) << 16);
}

// ---------------- aggregate C=64 (bf16 in, fp32 out, +bias): half-wave per node ----------------
__global__ __launch_bounds__(256) void aggregate64_kernel(
    const int* __restrict__ offsets, const int* __restrict__ sorted_src,
    const unsigned* __restrict__ val,   // bf16x2, 32 dwords/row
    const float* __restrict__ bias, float* __restrict__ out, int N)
{
    int node = blockIdx.x * 8 + (threadIdx.x >> 5);
    if (node >= N) return;
    int l = threadIdx.x & 31;
    int e = offsets[node];
    const int end = offsets[node + 1];
    float ax = 0.f, ay = 0.f;
    for (; e + 4 <= end; e += 4) {
        int s0 = sorted_src[e + 0], s1 = sorted_src[e + 1];
        int s2 = sorted_src[e + 2], s3 = sorted_src[e + 3];
        unsigned v0 = val[(size_t)s0 * 32 + l];
        unsigned v1 = val[(size_t)s1 * 32 + l];
        unsigned v2 = val[(size_t)s2 * 32 + l];
        unsigned v3 = val[(size_t)s3 * 32 + l];
        ax += (bf2f(v0 & 0xFFFF) + bf2f(v1 & 0xFFFF)) + (bf2f(v2 & 0xFFFF) + bf2f(v3 & 0xFFFF));
        ay += (bf2f(v0 >> 16) + bf2f(v1 >> 16)) + (bf2f(v2 >> 16) + bf2f(v3 >> 16));
    }
    for (; e < end; ++e) {
        unsigned v = val[(size_t)sorted_src[e] * 32 + l];
        ax += bf2f(v & 0xFFFF);
        ay += bf2f(v >> 16);
    }
    float2 r = make_float2(ax + bias[2 * l], ay + bias[2 * l + 1]);
    *(float2*)&out[(size_t)node * 64 + 2 * l] = r;
}

extern "C" void kernel_launch(void* const* d_in, const int* in_sizes, int n_in,
                              void* d_out, int out_size, void* d_ws, size_t ws_size,
                              hipStream_t stream) {
    const float* x  = (const float*)d_in[0];
    const int*   ei = (const int*)d_in[1];
    const float* W1 = (const float*)d_in[2];
    const float* b1 = (const float*)d_in[3];
    const float* W2 = (const float*)d_in[4];
    const float* b2 = (const float*)d_in[5];
    float* out = (float*)d_out;

    const int N = in_sizes[0] / 128;
    const int E = in_sizes[1] / 2;
    const int* src = ei;
    const int* dst = ei + E;

    char* ws = (char*)d_ws;
    size_t off = 0;
    auto alloc = [&](size_t bytes) {
        void* p = ws + off;
        off = (off + bytes + 255) & ~(size_t)255;
        return p;
    };
    int*   deg_src    = (int*)alloc((size_t)N * 4);
    int*   deg_dst    = (int*)alloc((size_t)N * 4);
    float* deg_inv    = (float*)alloc((size_t)N * 4);
    int*   offsets    = (int*)alloc((size_t)(N + 1) * 4);
    int*   cursor     = (int*)alloc((size_t)N * 4);
    int*   bsum       = (int*)alloc((size_t)256 * 4);
    int*   sorted_src = (int*)alloc((size_t)E * 4);
    unsigned short* h    = (unsigned short*)alloc((size_t)N * 128 * 2);  // bf16
    unsigned short* out1 = (unsigned short*)alloc((size_t)N * 128 * 2);  // bf16
    unsigned short* g    = h;  // reuse: h dead after aggregate1

    hipMemsetAsync(deg_src, 0, (size_t)N * 4, stream);
    hipMemsetAsync(deg_dst, 0, (size_t)N * 4, stream);

    hist2_kernel<<<(E + 255) / 256, 256, 0, stream>>>(src, dst, E, deg_src, deg_dst);
    deginv_kernel<<<(N + 255) / 256, 256, 0, stream>>>(deg_src, deg_inv, N);

    const int nb = (N + CHUNK - 1) / CHUNK;
    scan1_kernel<<<nb, BLK, 0, stream>>>(deg_dst, bsum, N);
    scan2_kernel<<<1, 64, 0, stream>>>(bsum, nb, offsets, N, E);
    scan3_kernel<<<nb, BLK, 0, stream>>>(deg_dst, bsum, offsets, cursor, N);
    build_kernel<<<(E + 255) / 256, 256, 0, stream>>>(src, dst, E, cursor, sorted_src);

    const int gblocks = (N + 127) / 128;
    // layer 1: h = bf16((x*deg_inv) @ W1);  out1 = relu(Agg(h) + b1)  [bf16]
    gemm_mfma_kernel<128, 1><<<gblocks, 256, 0, stream>>>(x, W1, deg_inv, h, N);
    aggregate128_kernel<<<(N + 3) / 4, 256, 0, stream>>>(offsets, sorted_src, (const unsigned*)h, b1,
                                                         (unsigned*)out1, N);
    // layer 2: g = bf16((out1*deg_inv) @ W2);  out = Agg(g) + b2  [fp32]
    gemm_mfma_kernel<64, 0><<<gblocks, 256, 0, stream>>>(out1, W2, deg_inv, g, N);
    aggregate64_kernel<<<(N + 7) / 8, 256, 0, stream>>>(offsets, sorted_src, (const unsigned*)g, b2, out, N);
}

// Round 4
// 394.154 us; speedup vs baseline: 11.2316x; 1.3454x over previous
//
#include <hip/hip_runtime.h>
#include <hip/hip_bf16.h>

// GCNEncoder: 2-layer GCN, out-degree norm. N=100000, E=1600000, 128->128->64, fp32 I/O.
// R4: replace single-pass counting sort (106MB write amplification, 130us) with a
// bucketed two-level sort: per-block contiguous pair runs, then one-block-per-bucket
// local sort that also emits per-node CSR offsets (kills the scan pipeline too).

typedef __attribute__((ext_vector_type(8))) short short8;
typedef __attribute__((ext_vector_type(4))) float floatx4;

__device__ inline unsigned short f2bf(float f) {
    union { float f; unsigned u; } v; v.f = f;
    unsigned r = v.u + 0x7FFF + ((v.u >> 16) & 1);  // RNE
    return (unsigned short)(r >> 16);
}
__device__ inline float bf2f(unsigned short b) {
    union { unsigned u; float f; } v; v.u = ((unsigned)b) << 16;
    return v.f;
}

#define NBMAX 512  // max dst-buckets (256 nodes each) -> supports N <= 131072

// ---- pass 1: deg_src histogram + bucket histogram (LDS-privatized) ----
__global__ __launch_bounds__(256) void hist_fused_kernel(
    const int* __restrict__ src, const int* __restrict__ dst, int E,
    int* __restrict__ deg_src, int* __restrict__ bucket_cnt, int NB)
{
    __shared__ int bh[NBMAX];
    for (int i = threadIdx.x; i < NB; i += 256) bh[i] = 0;
    __syncthreads();
    int stride = gridDim.x * 256;
    for (int i = blockIdx.x * 256 + threadIdx.x; i < E; i += stride) {
        atomicAdd(&deg_src[src[i]], 1);
        atomicAdd(&bh[dst[i] >> 8], 1);
    }
    __syncthreads();
    for (int i = threadIdx.x; i < NB; i += 256)
        if (bh[i]) atomicAdd(&bucket_cnt[i], bh[i]);
}

__global__ void deginv_kernel(const int* __restrict__ deg, float* __restrict__ deg_inv, int N) {
    int i = blockIdx.x * blockDim.x + threadIdx.x;
    if (i < N) {
        int d = deg[i];
        deg_inv[i] = 1.0f / (float)(d < 1 ? 1 : d);
    }
}

// ---- pass 2: scan bucket counts (single block) ----
__global__ __launch_bounds__(NBMAX) void bucket_scan_kernel(
    const int* __restrict__ bucket_cnt, int NB,
    int* __restrict__ bucket_off, int* __restrict__ gcursor,
    int* __restrict__ offsets, int N, int E)
{
    __shared__ int s[NBMAX];
    int t = threadIdx.x;
    int v = (t < NB) ? bucket_cnt[t] : 0;
    s[t] = v;
    __syncthreads();
    for (int o = 1; o < NBMAX; o <<= 1) {
        int add = (t >= o) ? s[t - o] : 0;
        __syncthreads();
        s[t] += add;
        __syncthreads();
    }
    int excl = s[t] - v;
    if (t < NB) { bucket_off[t] = excl; gcursor[t] = excl; }
    if (t == 0) { bucket_off[NB] = E; offsets[N] = E; }
}

// ---- pass 3: scatter packed (src,dst) pairs into bucket regions, block-contiguous runs ----
__global__ __launch_bounds__(256) void scatter_pairs_kernel(
    const int* __restrict__ src, const int* __restrict__ dst, int E,
    int* __restrict__ gcursor, unsigned long long* __restrict__ pairs, int NB)
{
    __shared__ int bh[NBMAX];
    __shared__ int bb[NBMAX];
    __shared__ int bc[NBMAX];
    for (int i = threadIdx.x; i < NB; i += 256) { bh[i] = 0; bc[i] = 0; }
    __syncthreads();
    const int e0 = blockIdx.x * 8192;
    const int e1 = min(e0 + 8192, E);
    for (int i = e0 + threadIdx.x; i < e1; i += 256)
        atomicAdd(&bh[dst[i] >> 8], 1);
    __syncthreads();
    for (int i = threadIdx.x; i < NB; i += 256)
        if (bh[i]) bb[i] = atomicAdd(&gcursor[i], bh[i]);
    __syncthreads();
    for (int i = e0 + threadIdx.x; i < e1; i += 256) {
        int d = dst[i];
        int b = d >> 8;
        int slot = atomicAdd(&bc[b], 1);
        pairs[(size_t)bb[b] + slot] =
            (unsigned long long)(unsigned)src[i] | ((unsigned long long)(unsigned)d << 32);
    }
}

// ---- pass 4: per-bucket counting sort -> sorted_src + per-node CSR offsets ----
__global__ __launch_bounds__(256) void bucket_sort_kernel(
    const unsigned long long* __restrict__ pairs, const int* __restrict__ bucket_off,
    int* __restrict__ offsets, int* __restrict__ sorted_src, int N)
{
    const int b = blockIdx.x;
    const int base = bucket_off[b];
    const int cnt = bucket_off[b + 1] - base;
    const int node0 = b << 8;
    const int t = threadIdx.x;
    __shared__ int hist[256];
    __shared__ int cur[256];
    __shared__ int pre[256];
    hist[t] = 0;
    __syncthreads();
    for (int i = t; i < cnt; i += 256) {
        int ld = (int)(pairs[base + i] >> 32) - node0;
        atomicAdd(&hist[ld], 1);
    }
    __syncthreads();
    int v = hist[t];
    pre[t] = v;
    __syncthreads();
    for (int o = 1; o < 256; o <<= 1) {
        int add = (t >= o) ? pre[t - o] : 0;
        __syncthreads();
        pre[t] += add;
        __syncthreads();
    }
    int excl = pre[t] - v;
    cur[t] = excl;
    if (node0 + t < N) offsets[node0 + t] = base + excl;
    __syncthreads();
    for (int i = t; i < cnt; i += 256) {
        unsigned long long p = pairs[base + i];
        int ld = (int)(p >> 32) - node0;
        int pos = atomicAdd(&cur[ld], 1);
        sorted_src[base + pos] = (int)(p & 0xFFFFFFFFu);
    }
}

// ---------------- MFMA GEMM: Cb[M x NC](bf16) = (A[M x 128] * scale[row]) @ W[128 x NC] ----------------
template <int NC, int AF>
__global__ __launch_bounds__(256) void gemm_mfma_kernel(
    const void* __restrict__ Ap, const float* __restrict__ W,
    const float* __restrict__ scale, unsigned short* __restrict__ Cb, int M)
{
    __shared__ unsigned short Al[128][136];
    __shared__ unsigned short Bl[NC][136];

    const int t = threadIdx.x;
    const int r0 = blockIdx.x * 128;

    for (int idx = t; idx < 128 * 32; idx += 256) {
        int r = idx >> 5, c4 = (idx & 31) << 2;
        int rg = r0 + r;
        ushort4 w;
        if (rg < M) {
            float s = scale[rg];
            float4 v;
            if (AF) {
                v = *(const float4*)&((const float*)Ap)[(size_t)rg * 128 + c4];
            } else {
                ushort4 u = *(const ushort4*)&((const unsigned short*)Ap)[(size_t)rg * 128 + c4];
                v = make_float4(bf2f(u.x), bf2f(u.y), bf2f(u.z), bf2f(u.w));
            }
            w.x = f2bf(v.x * s); w.y = f2bf(v.y * s);
            w.z = f2bf(v.z * s); w.w = f2bf(v.w * s);
        } else {
            w.x = w.y = w.z = w.w = 0;
        }
        *(ushort4*)&Al[r][c4] = w;
    }
    for (int idx = t; idx < 128 * (NC / 4); idx += 256) {
        int k = idx / (NC / 4), n4 = (idx % (NC / 4)) << 2;
        float4 v = *(const float4*)&W[(size_t)k * NC + n4];
        Bl[n4 + 0][k] = f2bf(v.x);
        Bl[n4 + 1][k] = f2bf(v.y);
        Bl[n4 + 2][k] = f2bf(v.z);
        Bl[n4 + 3][k] = f2bf(v.w);
    }
    __syncthreads();

    constexpr int NT = NC / 16;
    const int wm = t >> 6;
    const int lane = t & 63;
    const int lm = lane & 15;
    const int lk = (lane >> 4) * 8;

    floatx4 acc[2][NT];
#pragma unroll
    for (int i = 0; i < 2; ++i)
#pragma unroll
        for (int j = 0; j < NT; ++j) acc[i][j] = (floatx4){0.f, 0.f, 0.f, 0.f};

#pragma unroll
    for (int kk = 0; kk < 4; ++kk) {
        const int kb = kk * 32 + lk;
        short8 af[2];
        af[0] = *(const short8*)&Al[wm * 32 + lm][kb];
        af[1] = *(const short8*)&Al[wm * 32 + 16 + lm][kb];
        short8 bfr[NT];
#pragma unroll
        for (int j = 0; j < NT; ++j)
            bfr[j] = *(const short8*)&Bl[j * 16 + lm][kb];
#pragma unroll
        for (int i = 0; i < 2; ++i)
#pragma unroll
            for (int j = 0; j < NT; ++j)
                acc[i][j] = __builtin_amdgcn_mfma_f32_16x16x32_bf16(af[i], bfr[j], acc[i][j], 0, 0, 0);
    }

    const int rbase = r0 + wm * 32 + (lane >> 4) * 4;
#pragma unroll
    for (int i = 0; i < 2; ++i) {
#pragma unroll
        for (int reg = 0; reg < 4; ++reg) {
            int rg = rbase + i * 16 + reg;
            if (rg < M) {
#pragma unroll
                for (int j = 0; j < NT; ++j)
                    Cb[(size_t)rg * NC + j * 16 + lm] = f2bf(acc[i][j][reg]);
            }
        }
    }
}

// ---------------- aggregate C=128 (bf16 in/out, +bias, relu): one wave per node ----------------
__global__ __launch_bounds__(256) void aggregate128_kernel(
    const int* __restrict__ offsets, const int* __restrict__ sorted_src,
    const unsigned* __restrict__ val, const float* __restrict__ bias,
    unsigned* __restrict__ outb, int N)
{
    int node = blockIdx.x * 4 + (threadIdx.x >> 6);
    if (node >= N) return;
    int lane = threadIdx.x & 63;
    int e = offsets[node];
    const int end = offsets[node + 1];
    float ax = 0.f, ay = 0.f;
    for (; e + 4 <= end; e += 4) {
        int s0 = sorted_src[e + 0], s1 = sorted_src[e + 1];
        int s2 = sorted_src[e + 2], s3 = sorted_src[e + 3];
        unsigned v0 = val[(size_t)s0 * 64 + lane];
        unsigned v1 = val[(size_t)s1 * 64 + lane];
        unsigned v2 = val[(size_t)s2 * 64 + lane];
        unsigned v3 = val[(size_t)s3 * 64 + lane];
        ax += (bf2f(v0 & 0xFFFF) + bf2f(v1 & 0xFFFF)) + (bf2f(v2 & 0xFFFF) + bf2f(v3 & 0xFFFF));
        ay += (bf2f(v0 >> 16) + bf2f(v1 >> 16)) + (bf2f(v2 >> 16) + bf2f(v3 >> 16));
    }
    for (; e < end; ++e) {
        unsigned v = val[(size_t)sorted_src[e] * 64 + lane];
        ax += bf2f(v & 0xFFFF);
        ay += bf2f(v >> 16);
    }
    ax = fmaxf(ax + bias[2 * lane], 0.f);
    ay = fmaxf(ay + bias[2 * lane + 1], 0.f);
    outb[(size_t)node * 64 + lane] = (unsigned)f2bf(ax) | ((unsigned)f2bf(ay) << 16);
}

// ---------------- aggregate C=64 (bf16 in, fp32 out, +bias): half-wave per node ----------------
__global__ __launch_bounds__(256) void aggregate64_kernel(
    const int* __restrict__ offsets, const int* __restrict__ sorted_src,
    const unsigned* __restrict__ val, const float* __restrict__ bias,
    float* __restrict__ out, int N)
{
    int node = blockIdx.x * 8 + (threadIdx.x >> 5);
    if (node >= N) return;
    int l = threadIdx.x & 31;
    int e = offsets[node];
    const int end = offsets[node + 1];
    float ax = 0.f, ay = 0.f;
    for (; e + 4 <= end; e += 4) {
        int s0 = sorted_src[e + 0], s1 = sorted_src[e + 1];
        int s2 = sorted_src[e + 2], s3 = sorted_src[e + 3];
        unsigned v0 = val[(size_t)s0 * 32 + l];
        unsigned v1 = val[(size_t)s1 * 32 + l];
        unsigned v2 = val[(size_t)s2 * 32 + l];
        unsigned v3 = val[(size_t)s3 * 32 + l];
        ax += (bf2f(v0 & 0xFFFF) + bf2f(v1 & 0xFFFF)) + (bf2f(v2 & 0xFFFF) + bf2f(v3 & 0xFFFF));
        ay += (bf2f(v0 >> 16) + bf2f(v1 >> 16)) + (bf2f(v2 >> 16) + bf2f(v3 >> 16));
    }
    for (; e < end; ++e) {
        unsigned v = val[(size_t)sorted_src[e] * 32 + l];
        ax += bf2f(v & 0xFFFF);
        ay += bf2f(v >> 16);
    }
    float2 r = make_float2(ax + bias[2 * l], ay + bias[2 * l + 1]);
    *(float2*)&out[(size_t)node * 64 + 2 * l] = r;
}

extern "C" void kernel_launch(void* const* d_in, const int* in_sizes, int n_in,
                              void* d_out, int out_size, void* d_ws, size_t ws_size,
                              hipStream_t stream) {
    const float* x  = (const float*)d_in[0];
    const int*   ei = (const int*)d_in[1];
    const float* W1 = (const float*)d_in[2];
    const float* b1 = (const float*)d_in[3];
    const float* W2 = (const float*)d_in[4];
    const float* b2 = (const float*)d_in[5];
    float* out = (float*)d_out;

    const int N = in_sizes[0] / 128;
    const int E = in_sizes[1] / 2;
    const int* src = ei;
    const int* dst = ei + E;
    const int NB = (N + 255) >> 8;  // dst-buckets of 256 nodes; NB <= NBMAX

    char* ws = (char*)d_ws;
    size_t off = 0;
    auto alloc = [&](size_t bytes) {
        void* p = ws + off;
        off = (off + bytes + 255) & ~(size_t)255;
        return p;
    };
    int*   deg_src    = (int*)alloc((size_t)N * 4);
    float* deg_inv    = (float*)alloc((size_t)N * 4);
    int*   offsets    = (int*)alloc((size_t)(N + 1) * 4);
    int*   bucket_cnt = (int*)alloc((size_t)NBMAX * 4);
    int*   bucket_off = (int*)alloc((size_t)(NBMAX + 1) * 4);
    int*   gcursor    = (int*)alloc((size_t)NBMAX * 4);
    unsigned long long* pairs = (unsigned long long*)alloc((size_t)E * 8);
    int*   sorted_src = (int*)alloc((size_t)E * 4);
    unsigned short* h    = (unsigned short*)alloc((size_t)N * 128 * 2);
    unsigned short* out1 = (unsigned short*)alloc((size_t)N * 128 * 2);
    unsigned short* g    = h;  // h dead after aggregate1

    hipMemsetAsync(deg_src, 0, (size_t)N * 4, stream);
    hipMemsetAsync(bucket_cnt, 0, (size_t)NBMAX * 4, stream);

    hist_fused_kernel<<<512, 256, 0, stream>>>(src, dst, E, deg_src, bucket_cnt, NB);
    deginv_kernel<<<(N + 255) / 256, 256, 0, stream>>>(deg_src, deg_inv, N);
    bucket_scan_kernel<<<1, NBMAX, 0, stream>>>(bucket_cnt, NB, bucket_off, gcursor, offsets, N, E);
    scatter_pairs_kernel<<<(E + 8191) / 8192, 256, 0, stream>>>(src, dst, E, gcursor, pairs, NB);
    bucket_sort_kernel<<<NB, 256, 0, stream>>>(pairs, bucket_off, offsets, sorted_src, N);

    const int gblocks = (N + 127) / 128;
    gemm_mfma_kernel<128, 1><<<gblocks, 256, 0, stream>>>(x, W1, deg_inv, h, N);
    aggregate128_kernel<<<(N + 3) / 4, 256, 0, stream>>>(offsets, sorted_src, (const unsigned*)h, b1,
                                                         (unsigned*)out1, N);
    gemm_mfma_kernel<64, 0><<<gblocks, 256, 0, stream>>>(out1, W2, deg_inv, g, N);
    aggregate64_kernel<<<(N + 7) / 8, 256, 0, stream>>>(offsets, sorted_src, (const unsigned*)g, b2, out, N);
}

// Round 5
// 343.195 us; speedup vs baseline: 12.8994x; 1.1485x over previous
//
#include <hip/hip_runtime.h>
#include <hip/hip_bf16.h>

// GCNEncoder: 2-layer GCN, out-degree norm. N=100000, E=1600000, 128->128->64, fp32 I/O.
// R5: kill per-node global atomics (hist_fused: 50MB write-through, 74us) by bucketing
// src as well as dst. All per-node counting happens in LDS, one block per 256-node bucket.
// Pairs packed to 4B (local_dst<<24 | src), src-locals to 1B.

typedef __attribute__((ext_vector_type(8))) short short8;
typedef __attribute__((ext_vector_type(4))) float floatx4;

__device__ inline unsigned short f2bf(float f) {
    union { float f; unsigned u; } v; v.f = f;
    unsigned r = v.u + 0x7FFF + ((v.u >> 16) & 1);  // RNE
    return (unsigned short)(r >> 16);
}
__device__ inline float bf2f(unsigned short b) {
    union { unsigned u; float f; } v; v.u = ((unsigned)b) << 16;
    return v.f;
}

#define NBMAX 512  // max 256-node buckets -> N <= 131072 (and src < 2^24 for packing)

// ---- pass 1: bucket histograms for src and dst (LDS-privatized, padded global counters) ----
__global__ __launch_bounds__(256) void count_buckets_kernel(
    const int* __restrict__ src, const int* __restrict__ dst, int E,
    int* __restrict__ bcnt_s, int* __restrict__ bcnt_d, int NB)  // stride-16 padded
{
    __shared__ int hs[NBMAX], hd[NBMAX];
    for (int i = threadIdx.x; i < NB; i += 256) { hs[i] = 0; hd[i] = 0; }
    __syncthreads();
    int stride = gridDim.x * 256;
    for (int i = blockIdx.x * 256 + threadIdx.x; i < E; i += stride) {
        atomicAdd(&hs[src[i] >> 8], 1);
        atomicAdd(&hd[dst[i] >> 8], 1);
    }
    __syncthreads();
    for (int i = threadIdx.x; i < NB; i += 256) {
        if (hs[i]) atomicAdd(&bcnt_s[i * 16], hs[i]);
        if (hd[i]) atomicAdd(&bcnt_d[i * 16], hd[i]);
    }
}

// ---- pass 2: scan both bucket-count arrays (single block) ----
__global__ __launch_bounds__(NBMAX) void bucket_scan_kernel(
    const int* __restrict__ bcnt_s, const int* __restrict__ bcnt_d, int NB,
    int* __restrict__ boff_s, int* __restrict__ gcur_s,
    int* __restrict__ boff_d, int* __restrict__ gcur_d,
    int* __restrict__ offsets, int N, int E)
{
    __shared__ int s[NBMAX];
    int t = threadIdx.x;
    // dst buckets
    int v = (t < NB) ? bcnt_d[t * 16] : 0;
    s[t] = v;
    __syncthreads();
    for (int o = 1; o < NBMAX; o <<= 1) {
        int a = (t >= o) ? s[t - o] : 0;
        __syncthreads();
        s[t] += a;
        __syncthreads();
    }
    int excl = s[t] - v;
    if (t < NB) { boff_d[t] = excl; gcur_d[t] = excl; }
    if (t == 0) { boff_d[NB] = E; offsets[N] = E; }
    __syncthreads();
    // src buckets
    v = (t < NB) ? bcnt_s[t * 16] : 0;
    s[t] = v;
    __syncthreads();
    for (int o = 1; o < NBMAX; o <<= 1) {
        int a = (t >= o) ? s[t - o] : 0;
        __syncthreads();
        s[t] += a;
        __syncthreads();
    }
    excl = s[t] - v;
    if (t < NB) { boff_s[t] = excl; gcur_s[t] = excl; }
    if (t == 0) boff_s[NB] = E;
}

// ---- pass 3: scatter packed pairs (dst-bucketed) + src low-bytes (src-bucketed) ----
__global__ __launch_bounds__(256) void scatter2_kernel(
    const int* __restrict__ src, const int* __restrict__ dst, int E,
    int* __restrict__ gcur_d, int* __restrict__ gcur_s,
    unsigned* __restrict__ pairs, unsigned char* __restrict__ srcs_b, int NB)
{
    __shared__ int hd[NBMAX], bd[NBMAX], cd_[NBMAX];
    __shared__ int hs[NBMAX], bs[NBMAX], cs_[NBMAX];
    for (int i = threadIdx.x; i < NB; i += 256) { hd[i] = 0; cd_[i] = 0; hs[i] = 0; cs_[i] = 0; }
    __syncthreads();
    const int e0 = blockIdx.x * 8192;
    const int e1 = min(e0 + 8192, E);
    for (int i = e0 + threadIdx.x; i < e1; i += 256) {
        atomicAdd(&hd[dst[i] >> 8], 1);
        atomicAdd(&hs[src[i] >> 8], 1);
    }
    __syncthreads();
    for (int i = threadIdx.x; i < NB; i += 256) {
        if (hd[i]) bd[i] = atomicAdd(&gcur_d[i], hd[i]);
        if (hs[i]) bs[i] = atomicAdd(&gcur_s[i], hs[i]);
    }
    __syncthreads();
    for (int i = e0 + threadIdx.x; i < e1; i += 256) {
        int sv = src[i], dv = dst[i];
        int b = dv >> 8;
        int slot = atomicAdd(&cd_[b], 1);
        pairs[(size_t)bd[b] + slot] = ((unsigned)(dv & 255) << 24) | (unsigned)sv;
        int b2 = sv >> 8;
        int slot2 = atomicAdd(&cs_[b2], 1);
        srcs_b[(size_t)bs[b2] + slot2] = (unsigned char)(sv & 255);
    }
}

// ---- pass 4a: per-dst-bucket counting sort -> sorted_src + per-node CSR offsets ----
__global__ __launch_bounds__(256) void bucket_sort_kernel(
    const unsigned* __restrict__ pairs, const int* __restrict__ boff_d,
    int* __restrict__ offsets, int* __restrict__ sorted_src, int N)
{
    const int b = blockIdx.x;
    const int base = boff_d[b];
    const int cnt = boff_d[b + 1] - base;
    const int node0 = b << 8;
    const int t = threadIdx.x;
    __shared__ int hist[256];
    __shared__ int cur[256];
    __shared__ int pre[256];
    hist[t] = 0;
    __syncthreads();
    for (int i = t; i < cnt; i += 256)
        atomicAdd(&hist[pairs[base + i] >> 24], 1);
    __syncthreads();
    int v = hist[t];
    pre[t] = v;
    __syncthreads();
    for (int o = 1; o < 256; o <<= 1) {
        int add = (t >= o) ? pre[t - o] : 0;
        __syncthreads();
        pre[t] += add;
        __syncthreads();
    }
    int excl = pre[t] - v;
    cur[t] = excl;
    if (node0 + t < N) offsets[node0 + t] = base + excl;
    __syncthreads();
    for (int i = t; i < cnt; i += 256) {
        unsigned p = pairs[base + i];
        int pos = atomicAdd(&cur[p >> 24], 1);
        sorted_src[base + pos] = (int)(p & 0xFFFFFFu);
    }
}

// ---- pass 4b: per-src-bucket histogram -> deg_inv (coalesced write, no scan needed) ----
__global__ __launch_bounds__(256) void deginv_bucket_kernel(
    const unsigned char* __restrict__ srcs_b, const int* __restrict__ boff_s,
    float* __restrict__ deg_inv, int N)
{
    const int b = blockIdx.x;
    const int base = boff_s[b];
    const int cnt = boff_s[b + 1] - base;
    const int node0 = b << 8;
    const int t = threadIdx.x;
    __shared__ int hist[256];
    hist[t] = 0;
    __syncthreads();
    for (int i = t; i < cnt; i += 256)
        atomicAdd(&hist[srcs_b[base + i]], 1);
    __syncthreads();
    if (node0 + t < N) {
        int d = hist[t];
        deg_inv[node0 + t] = 1.0f / (float)(d < 1 ? 1 : d);
    }
}

// ---------------- MFMA GEMM: Cb[M x NC](bf16) = (A[M x 128] * scale[row]) @ W[128 x NC] ----------------
template <int NC, int AF>
__global__ __launch_bounds__(256) void gemm_mfma_kernel(
    const void* __restrict__ Ap, const float* __restrict__ W,
    const float* __restrict__ scale, unsigned short* __restrict__ Cb, int M)
{
    __shared__ unsigned short Al[128][136];
    __shared__ unsigned short Bl[NC][136];

    const int t = threadIdx.x;
    const int r0 = blockIdx.x * 128;

    for (int idx = t; idx < 128 * 32; idx += 256) {
        int r = idx >> 5, c4 = (idx & 31) << 2;
        int rg = r0 + r;
        ushort4 w;
        if (rg < M) {
            float s = scale[rg];
            float4 v;
            if (AF) {
                v = *(const float4*)&((const float*)Ap)[(size_t)rg * 128 + c4];
            } else {
                ushort4 u = *(const ushort4*)&((const unsigned short*)Ap)[(size_t)rg * 128 + c4];
                v = make_float4(bf2f(u.x), bf2f(u.y), bf2f(u.z), bf2f(u.w));
            }
            w.x = f2bf(v.x * s); w.y = f2bf(v.y * s);
            w.z = f2bf(v.z * s); w.w = f2bf(v.w * s);
        } else {
            w.x = w.y = w.z = w.w = 0;
        }
        *(ushort4*)&Al[r][c4] = w;
    }
    for (int idx = t; idx < 128 * (NC / 4); idx += 256) {
        int k = idx / (NC / 4), n4 = (idx % (NC / 4)) << 2;
        float4 v = *(const float4*)&W[(size_t)k * NC + n4];
        Bl[n4 + 0][k] = f2bf(v.x);
        Bl[n4 + 1][k] = f2bf(v.y);
        Bl[n4 + 2][k] = f2bf(v.z);
        Bl[n4 + 3][k] = f2bf(v.w);
    }
    __syncthreads();

    constexpr int NT = NC / 16;
    const int wm = t >> 6;
    const int lane = t & 63;
    const int lm = lane & 15;
    const int lk = (lane >> 4) * 8;

    floatx4 acc[2][NT];
#pragma unroll
    for (int i = 0; i < 2; ++i)
#pragma unroll
        for (int j = 0; j < NT; ++j) acc[i][j] = (floatx4){0.f, 0.f, 0.f, 0.f};

#pragma unroll
    for (int kk = 0; kk < 4; ++kk) {
        const int kb = kk * 32 + lk;
        short8 af[2];
        af[0] = *(const short8*)&Al[wm * 32 + lm][kb];
        af[1] = *(const short8*)&Al[wm * 32 + 16 + lm][kb];
        short8 bfr[NT];
#pragma unroll
        for (int j = 0; j < NT; ++j)
            bfr[j] = *(const short8*)&Bl[j * 16 + lm][kb];
#pragma unroll
        for (int i = 0; i < 2; ++i)
#pragma unroll
            for (int j = 0; j < NT; ++j)
                acc[i][j] = __builtin_amdgcn_mfma_f32_16x16x32_bf16(af[i], bfr[j], acc[i][j], 0, 0, 0);
    }

    const int rbase = r0 + wm * 32 + (lane >> 4) * 4;
#pragma unroll
    for (int i = 0; i < 2; ++i) {
#pragma unroll
        for (int reg = 0; reg < 4; ++reg) {
            int rg = rbase + i * 16 + reg;
            if (rg < M) {
#pragma unroll
                for (int j = 0; j < NT; ++j)
                    Cb[(size_t)rg * NC + j * 16 + lm] = f2bf(acc[i][j][reg]);
            }
        }
    }
}

// ---------------- aggregate C=128 (bf16 in/out, +bias, relu): half-wave per node, uint2 loads ----------------
__global__ __launch_bounds__(256) void aggregate128_kernel(
    const int* __restrict__ offsets, const int* __restrict__ sorted_src,
    const unsigned* __restrict__ val, const float* __restrict__ bias,
    unsigned* __restrict__ outb, int N)
{
    int node = blockIdx.x * 8 + (threadIdx.x >> 5);
    if (node >= N) return;
    int l = threadIdx.x & 31;
    int e = offsets[node];
    const int end = offsets[node + 1];
    float a0 = 0.f, a1 = 0.f, a2 = 0.f, a3 = 0.f;
    for (; e + 4 <= end; e += 4) {
        int s0 = sorted_src[e + 0], s1 = sorted_src[e + 1];
        int s2 = sorted_src[e + 2], s3 = sorted_src[e + 3];
        uint2 v0 = *(const uint2*)&val[(size_t)s0 * 64 + 2 * l];
        uint2 v1 = *(const uint2*)&val[(size_t)s1 * 64 + 2 * l];
        uint2 v2 = *(const uint2*)&val[(size_t)s2 * 64 + 2 * l];
        uint2 v3 = *(const uint2*)&val[(size_t)s3 * 64 + 2 * l];
        a0 += (bf2f(v0.x & 0xFFFF) + bf2f(v1.x & 0xFFFF)) + (bf2f(v2.x & 0xFFFF) + bf2f(v3.x & 0xFFFF));
        a1 += (bf2f(v0.x >> 16) + bf2f(v1.x >> 16)) + (bf2f(v2.x >> 16) + bf2f(v3.x >> 16));
        a2 += (bf2f(v0.y & 0xFFFF) + bf2f(v1.y & 0xFFFF)) + (bf2f(v2.y & 0xFFFF) + bf2f(v3.y & 0xFFFF));
        a3 += (bf2f(v0.y >> 16) + bf2f(v1.y >> 16)) + (bf2f(v2.y >> 16) + bf2f(v3.y >> 16));
    }
    for (; e < end; ++e) {
        uint2 v = *(const uint2*)&val[(size_t)sorted_src[e] * 64 + 2 * l];
        a0 += bf2f(v.x & 0xFFFF);
        a1 += bf2f(v.x >> 16);
        a2 += bf2f(v.y & 0xFFFF);
        a3 += bf2f(v.y >> 16);
    }
    a0 = fmaxf(a0 + bias[4 * l + 0], 0.f);
    a1 = fmaxf(a1 + bias[4 * l + 1], 0.f);
    a2 = fmaxf(a2 + bias[4 * l + 2], 0.f);
    a3 = fmaxf(a3 + bias[4 * l + 3], 0.f);
    uint2 r;
    r.x = (unsigned)f2bf(a0) | ((unsigned)f2bf(a1) << 16);
    r.y = (unsigned)f2bf(a2) | ((unsigned)f2bf(a3) << 16);
    *(uint2*)&outb[(size_t)node * 64 + 2 * l] = r;
}

// ---------------- aggregate C=64 (bf16 in, fp32 out, +bias): half-wave per node ----------------
__global__ __launch_bounds__(256) void aggregate64_kernel(
    const int* __restrict__ offsets, const int* __restrict__ sorted_src,
    const unsigned* __restrict__ val, const float* __restrict__ bias,
    float* __restrict__ out, int N)
{
    int node = blockIdx.x * 8 + (threadIdx.x >> 5);
    if (node >= N) return;
    int l = threadIdx.x & 31;
    int e = offsets[node];
    const int end = offsets[node + 1];
    float ax = 0.f, ay = 0.f;
    for (; e + 4 <= end; e += 4) {
        int s0 = sorted_src[e + 0], s1 = sorted_src[e + 1];
        int s2 = sorted_src[e + 2], s3 = sorted_src[e + 3];
        unsigned v0 = val[(size_t)s0 * 32 + l];
        unsigned v1 = val[(size_t)s1 * 32 + l];
        unsigned v2 = val[(size_t)s2 * 32 + l];
        unsigned v3 = val[(size_t)s3 * 32 + l];
        ax += (bf2f(v0 & 0xFFFF) + bf2f(v1 & 0xFFFF)) + (bf2f(v2 & 0xFFFF) + bf2f(v3 & 0xFFFF));
        ay += (bf2f(v0 >> 16) + bf2f(v1 >> 16)) + (bf2f(v2 >> 16) + bf2f(v3 >> 16));
    }
    for (; e < end; ++e) {
        unsigned v = val[(size_t)sorted_src[e] * 32 + l];
        ax += bf2f(v & 0xFFFF);
        ay += bf2f(v >> 16);
    }
    float2 r = make_float2(ax + bias[2 * l], ay + bias[2 * l + 1]);
    *(float2*)&out[(size_t)node * 64 + 2 * l] = r;
}

extern "C" void kernel_launch(void* const* d_in, const int* in_sizes, int n_in,
                              void* d_out, int out_size, void* d_ws, size_t ws_size,
                              hipStream_t stream) {
    const float* x  = (const float*)d_in[0];
    const int*   ei = (const int*)d_in[1];
    const float* W1 = (const float*)d_in[2];
    const float* b1 = (const float*)d_in[3];
    const float* W2 = (const float*)d_in[4];
    const float* b2 = (const float*)d_in[5];
    float* out = (float*)d_out;

    const int N = in_sizes[0] / 128;
    const int E = in_sizes[1] / 2;
    const int* src = ei;
    const int* dst = ei + E;
    const int NB = (N + 255) >> 8;

    char* ws = (char*)d_ws;
    size_t off = 0;
    auto alloc = [&](size_t bytes) {
        void* p = ws + off;
        off = (off + bytes + 255) & ~(size_t)255;
        return p;
    };
    float* deg_inv  = (float*)alloc((size_t)N * 4);
    int*   offsets  = (int*)alloc((size_t)(N + 1) * 4);
    int*   bcnt_s   = (int*)alloc((size_t)NBMAX * 16 * 4);
    int*   bcnt_d   = (int*)alloc((size_t)NBMAX * 16 * 4);
    int*   boff_s   = (int*)alloc((size_t)(NBMAX + 1) * 4);
    int*   boff_d   = (int*)alloc((size_t)(NBMAX + 1) * 4);
    int*   gcur_s   = (int*)alloc((size_t)NBMAX * 4);
    int*   gcur_d   = (int*)alloc((size_t)NBMAX * 4);
    unsigned*      pairs   = (unsigned*)alloc((size_t)E * 4);
    unsigned char* srcs_b  = (unsigned char*)alloc((size_t)E);
    int*   sorted_src = (int*)alloc((size_t)E * 4);
    unsigned short* h    = (unsigned short*)alloc((size_t)N * 128 * 2);
    unsigned short* out1 = (unsigned short*)alloc((size_t)N * 128 * 2);
    unsigned short* g    = h;  // h dead after aggregate1

    hipMemsetAsync(bcnt_s, 0, (size_t)NBMAX * 16 * 4, stream);
    hipMemsetAsync(bcnt_d, 0, (size_t)NBMAX * 16 * 4, stream);

    count_buckets_kernel<<<256, 256, 0, stream>>>(src, dst, E, bcnt_s, bcnt_d, NB);
    bucket_scan_kernel<<<1, NBMAX, 0, stream>>>(bcnt_s, bcnt_d, NB, boff_s, gcur_s,
                                                boff_d, gcur_d, offsets, N, E);
    scatter2_kernel<<<(E + 8191) / 8192, 256, 0, stream>>>(src, dst, E, gcur_d, gcur_s,
                                                           pairs, srcs_b, NB);
    bucket_sort_kernel<<<NB, 256, 0, stream>>>(pairs, boff_d, offsets, sorted_src, N);
    deginv_bucket_kernel<<<NB, 256, 0, stream>>>(srcs_b, boff_s, deg_inv, N);

    const int gblocks = (N + 127) / 128;
    gemm_mfma_kernel<128, 1><<<gblocks, 256, 0, stream>>>(x, W1, deg_inv, h, N);
    aggregate128_kernel<<<(N + 7) / 8, 256, 0, stream>>>(offsets, sorted_src, (const unsigned*)h, b1,
                                                         (unsigned*)out1, N);
    gemm_mfma_kernel<64, 0><<<gblocks, 256, 0, stream>>>(out1, W2, deg_inv, g, N);
    aggregate64_kernel<<<(N + 7) / 8, 256, 0, stream>>>(offsets, sorted_src, (const unsigned*)g, b2, out, N);
}

// Round 6
// 329.157 us; speedup vs baseline: 13.4495x; 1.0426x over previous
//
#include <hip/hip_runtime.h>
#include <hip/hip_bf16.h>

// GCNEncoder: 2-layer GCN, out-degree norm. N=100000, E=1600000, 128->128->64, fp32 I/O.
// R6: fixed-capacity bucket sort (CAP=8192 per 256-node bucket, ~2x mean occupancy of 4092)
// eliminates the pre-count + scan passes. Per-node CSR emitted as packed (start,end) int2.
// bucket_sort + deginv fused. Aggregate inner loops unrolled 8x for gather MLP.
// aggregate128 FETCH (~177MB) is structural: random src => every XCD's L2 must fill ~all of h.

typedef __attribute__((ext_vector_type(8))) short short8;
typedef __attribute__((ext_vector_type(4))) float floatx4;

__device__ inline unsigned short f2bf(float f) {
    union { float f; unsigned u; } v; v.f = f;
    unsigned r = v.u + 0x7FFF + ((v.u >> 16) & 1);  // RNE
    return (unsigned short)(r >> 16);
}
__device__ inline float bf2f(unsigned short b) {
    union { unsigned u; float f; } v; v.u = ((unsigned)b) << 16;
    return v.f;
}

#define NBMAX 512   // max 256-node buckets -> N <= 131072 (src < 2^24 for packing)
#define CAP   8192  // fixed bucket capacity; mean load 4092 for E=1.6M/NB=391 -> 2x headroom

// ---- pass 1: per-block LDS bucket histograms; reserve bucket runs via global cursors
//      (count from zero -> no pre-count/scan); scatter packed dst-pairs + src low-bytes.
__global__ __launch_bounds__(256) void scatter2_kernel(
    const int* __restrict__ src, const int* __restrict__ dst, int E,
    int* __restrict__ cnt_d, int* __restrict__ cnt_s,   // stride-16 padded atomic cursors
    unsigned* __restrict__ pairs, unsigned char* __restrict__ srcs_b, int NB)
{
    __shared__ int hd[NBMAX], bd[NBMAX], cd_[NBMAX];
    __shared__ int hs[NBMAX], bs[NBMAX], cs_[NBMAX];
    for (int i = threadIdx.x; i < NB; i += 256) { hd[i] = 0; cd_[i] = 0; hs[i] = 0; cs_[i] = 0; }
    __syncthreads();
    const int e0 = blockIdx.x * 8192;
    const int e1 = min(e0 + 8192, E);
    for (int i = e0 + threadIdx.x; i < e1; i += 256) {
        atomicAdd(&hd[dst[i] >> 8], 1);
        atomicAdd(&hs[src[i] >> 8], 1);
    }
    __syncthreads();
    for (int i = threadIdx.x; i < NB; i += 256) {
        if (hd[i]) bd[i] = atomicAdd(&cnt_d[i * 16], hd[i]);
        if (hs[i]) bs[i] = atomicAdd(&cnt_s[i * 16], hs[i]);
    }
    __syncthreads();
    for (int i = e0 + threadIdx.x; i < e1; i += 256) {
        int sv = src[i], dv = dst[i];
        int b = dv >> 8;
        int slot = atomicAdd(&cd_[b], 1);
        pairs[(size_t)b * CAP + bd[b] + slot] = ((unsigned)(dv & 255) << 24) | (unsigned)sv;
        int b2 = sv >> 8;
        int slot2 = atomicAdd(&cs_[b2], 1);
        srcs_b[(size_t)b2 * CAP + bs[b2] + slot2] = (unsigned char)(sv & 255);
    }
}

// ---- pass 2 (fused): per-bucket dst counting sort -> sorted_src + (start,end) per node;
//      then per-bucket src histogram -> deg_inv.
__global__ __launch_bounds__(256) void bucket_finalize_kernel(
    const unsigned* __restrict__ pairs, const unsigned char* __restrict__ srcs_b,
    const int* __restrict__ cnt_d, const int* __restrict__ cnt_s,
    int* __restrict__ sorted_src, int2* __restrict__ se,
    float* __restrict__ deg_inv, int N)
{
    const int b = blockIdx.x;
    const int node0 = b << 8;
    const int t = threadIdx.x;
    const size_t base = (size_t)b * CAP;
    __shared__ int hist[256];
    __shared__ int cur[256];
    __shared__ int pre[256];

    // --- phase 1: dst sort ---
    const int cd = cnt_d[b * 16];
    hist[t] = 0;
    __syncthreads();
    for (int i = t; i < cd; i += 256)
        atomicAdd(&hist[pairs[base + i] >> 24], 1);
    __syncthreads();
    int v = hist[t];
    pre[t] = v;
    __syncthreads();
    for (int o = 1; o < 256; o <<= 1) {
        int add = (t >= o) ? pre[t - o] : 0;
        __syncthreads();
        pre[t] += add;
        __syncthreads();
    }
    int excl = pre[t] - v;
    cur[t] = excl;
    if (node0 + t < N)
        se[node0 + t] = make_int2((int)base + excl, (int)base + excl + v);
    __syncthreads();
    for (int i = t; i < cd; i += 256) {
        unsigned p = pairs[base + i];
        int pos = atomicAdd(&cur[p >> 24], 1);
        sorted_src[base + pos] = (int)(p & 0xFFFFFFu);
    }

    // --- phase 2: src degree -> deg_inv ---
    __syncthreads();
    hist[t] = 0;
    __syncthreads();
    const int cs = cnt_s[b * 16];
    for (int i = t; i < cs; i += 256)
        atomicAdd(&hist[srcs_b[base + i]], 1);
    __syncthreads();
    if (node0 + t < N) {
        int d = hist[t];
        deg_inv[node0 + t] = 1.0f / (float)(d < 1 ? 1 : d);
    }
}

// ---------------- MFMA GEMM: Cb[M x NC](bf16) = (A[M x 128] * scale[row]) @ W[128 x NC] ----------------
template <int NC, int AF>
__global__ __launch_bounds__(256) void gemm_mfma_kernel(
    const void* __restrict__ Ap, const float* __restrict__ W,
    const float* __restrict__ scale, unsigned short* __restrict__ Cb, int M)
{
    __shared__ unsigned short Al[128][136];
    __shared__ unsigned short Bl[NC][136];

    const int t = threadIdx.x;
    const int r0 = blockIdx.x * 128;

    for (int idx = t; idx < 128 * 32; idx += 256) {
        int r = idx >> 5, c4 = (idx & 31) << 2;
        int rg = r0 + r;
        ushort4 w;
        if (rg < M) {
            float s = scale[rg];
            float4 v;
            if (AF) {
                v = *(const float4*)&((const float*)Ap)[(size_t)rg * 128 + c4];
            } else {
                ushort4 u = *(const ushort4*)&((const unsigned short*)Ap)[(size_t)rg * 128 + c4];
                v = make_float4(bf2f(u.x), bf2f(u.y), bf2f(u.z), bf2f(u.w));
            }
            w.x = f2bf(v.x * s); w.y = f2bf(v.y * s);
            w.z = f2bf(v.z * s); w.w = f2bf(v.w * s);
        } else {
            w.x = w.y = w.z = w.w = 0;
        }
        *(ushort4*)&Al[r][c4] = w;
    }
    for (int idx = t; idx < 128 * (NC / 4); idx += 256) {
        int k = idx / (NC / 4), n4 = (idx % (NC / 4)) << 2;
        float4 v = *(const float4*)&W[(size_t)k * NC + n4];
        Bl[n4 + 0][k] = f2bf(v.x);
        Bl[n4 + 1][k] = f2bf(v.y);
        Bl[n4 + 2][k] = f2bf(v.z);
        Bl[n4 + 3][k] = f2bf(v.w);
    }
    __syncthreads();

    constexpr int NT = NC / 16;
    const int wm = t >> 6;
    const int lane = t & 63;
    const int lm = lane & 15;
    const int lk = (lane >> 4) * 8;

    floatx4 acc[2][NT];
#pragma unroll
    for (int i = 0; i < 2; ++i)
#pragma unroll
        for (int j = 0; j < NT; ++j) acc[i][j] = (floatx4){0.f, 0.f, 0.f, 0.f};

#pragma unroll
    for (int kk = 0; kk < 4; ++kk) {
        const int kb = kk * 32 + lk;
        short8 af[2];
        af[0] = *(const short8*)&Al[wm * 32 + lm][kb];
        af[1] = *(const short8*)&Al[wm * 32 + 16 + lm][kb];
        short8 bfr[NT];
#pragma unroll
        for (int j = 0; j < NT; ++j)
            bfr[j] = *(const short8*)&Bl[j * 16 + lm][kb];
#pragma unroll
        for (int i = 0; i < 2; ++i)
#pragma unroll
            for (int j = 0; j < NT; ++j)
                acc[i][j] = __builtin_amdgcn_mfma_f32_16x16x32_bf16(af[i], bfr[j], acc[i][j], 0, 0, 0);
    }

    const int rbase = r0 + wm * 32 + (lane >> 4) * 4;
#pragma unroll
    for (int i = 0; i < 2; ++i) {
#pragma unroll
        for (int reg = 0; reg < 4; ++reg) {
            int rg = rbase + i * 16 + reg;
            if (rg < M) {
#pragma unroll
                for (int j = 0; j < NT; ++j)
                    Cb[(size_t)rg * NC + j * 16 + lm] = f2bf(acc[i][j][reg]);
            }
        }
    }
}

// ---------------- aggregate C=128 (bf16 in/out, +bias, relu): half-wave per node, unroll 8 ----------------
__global__ __launch_bounds__(256) void aggregate128_kernel(
    const int2* __restrict__ se, const int* __restrict__ sorted_src,
    const unsigned* __restrict__ val, const float* __restrict__ bias,
    unsigned* __restrict__ outb, int N)
{
    int node = blockIdx.x * 8 + (threadIdx.x >> 5);
    if (node >= N) return;
    int l = threadIdx.x & 31;
    int2 r = se[node];
    int e = r.x;
    const int end = r.y;
    float a0 = 0.f, a1 = 0.f, a2 = 0.f, a3 = 0.f;
    for (; e + 8 <= end; e += 8) {
        uint2 v[8];
#pragma unroll
        for (int k = 0; k < 8; ++k) {
            int s = sorted_src[e + k];
            v[k] = *(const uint2*)&val[(size_t)s * 64 + 2 * l];
        }
#pragma unroll
        for (int k = 0; k < 8; ++k) {
            a0 += bf2f(v[k].x & 0xFFFF);
            a1 += bf2f(v[k].x >> 16);
            a2 += bf2f(v[k].y & 0xFFFF);
            a3 += bf2f(v[k].y >> 16);
        }
    }
    for (; e < end; ++e) {
        uint2 v = *(const uint2*)&val[(size_t)sorted_src[e] * 64 + 2 * l];
        a0 += bf2f(v.x & 0xFFFF);
        a1 += bf2f(v.x >> 16);
        a2 += bf2f(v.y & 0xFFFF);
        a3 += bf2f(v.y >> 16);
    }
    float4 bv = *(const float4*)&bias[4 * l];
    a0 = fmaxf(a0 + bv.x, 0.f);
    a1 = fmaxf(a1 + bv.y, 0.f);
    a2 = fmaxf(a2 + bv.z, 0.f);
    a3 = fmaxf(a3 + bv.w, 0.f);
    uint2 o;
    o.x = (unsigned)f2bf(a0) | ((unsigned)f2bf(a1) << 16);
    o.y = (unsigned)f2bf(a2) | ((unsigned)f2bf(a3) << 16);
    *(uint2*)&outb[(size_t)node * 64 + 2 * l] = o;
}

// ---------------- aggregate C=64 (bf16 in, fp32 out, +bias): half-wave per node, unroll 8 ----------------
__global__ __launch_bounds__(256) void aggregate64_kernel(
    const int2* __restrict__ se, const int* __restrict__ sorted_src,
    const unsigned* __restrict__ val, const float* __restrict__ bias,
    float* __restrict__ out, int N)
{
    int node = blockIdx.x * 8 + (threadIdx.x >> 5);
    if (node >= N) return;
    int l = threadIdx.x & 31;
    int2 r = se[node];
    int e = r.x;
    const int end = r.y;
    float ax = 0.f, ay = 0.f;
    for (; e + 8 <= end; e += 8) {
        unsigned v[8];
#pragma unroll
        for (int k = 0; k < 8; ++k) {
            int s = sorted_src[e + k];
            v[k] = val[(size_t)s * 32 + l];
        }
#pragma unroll
        for (int k = 0; k < 8; ++k) {
            ax += bf2f(v[k] & 0xFFFF);
            ay += bf2f(v[k] >> 16);
        }
    }
    for (; e < end; ++e) {
        unsigned v = val[(size_t)sorted_src[e] * 32 + l];
        ax += bf2f(v & 0xFFFF);
        ay += bf2f(v >> 16);
    }
    float2 o = make_float2(ax + bias[2 * l], ay + bias[2 * l + 1]);
    *(float2*)&out[(size_t)node * 64 + 2 * l] = o;
}

extern "C" void kernel_launch(void* const* d_in, const int* in_sizes, int n_in,
                              void* d_out, int out_size, void* d_ws, size_t ws_size,
                              hipStream_t stream) {
    const float* x  = (const float*)d_in[0];
    const int*   ei = (const int*)d_in[1];
    const float* W1 = (const float*)d_in[2];
    const float* b1 = (const float*)d_in[3];
    const float* W2 = (const float*)d_in[4];
    const float* b2 = (const float*)d_in[5];
    float* out = (float*)d_out;

    const int N = in_sizes[0] / 128;
    const int E = in_sizes[1] / 2;
    const int* src = ei;
    const int* dst = ei + E;
    const int NB = (N + 255) >> 8;

    char* ws = (char*)d_ws;
    size_t off = 0;
    auto alloc = [&](size_t bytes) {
        void* p = ws + off;
        off = (off + bytes + 255) & ~(size_t)255;
        return p;
    };
    float* deg_inv  = (float*)alloc((size_t)N * 4);
    int2*  se       = (int2*)alloc((size_t)N * 8);
    int*   cnt_d    = (int*)alloc((size_t)NBMAX * 16 * 4);
    int*   cnt_s    = (int*)alloc((size_t)NBMAX * 16 * 4);
    unsigned*      pairs  = (unsigned*)alloc((size_t)NBMAX * CAP * 4);
    unsigned char* srcs_b = (unsigned char*)alloc((size_t)NBMAX * CAP);
    int*   sorted_src = (int*)alloc((size_t)NBMAX * CAP * 4);
    unsigned short* h    = (unsigned short*)alloc((size_t)N * 128 * 2);
    unsigned short* out1 = (unsigned short*)alloc((size_t)N * 128 * 2);
    unsigned short* g    = h;  // h dead after aggregate1

    hipMemsetAsync(cnt_d, 0, (size_t)NBMAX * 16 * 4, stream);
    hipMemsetAsync(cnt_s, 0, (size_t)NBMAX * 16 * 4, stream);

    scatter2_kernel<<<(E + 8191) / 8192, 256, 0, stream>>>(src, dst, E, cnt_d, cnt_s,
                                                           pairs, srcs_b, NB);
    bucket_finalize_kernel<<<NB, 256, 0, stream>>>(pairs, srcs_b, cnt_d, cnt_s,
                                                   sorted_src, se, deg_inv, N);

    const int gblocks = (N + 127) / 128;
    gemm_mfma_kernel<128, 1><<<gblocks, 256, 0, stream>>>(x, W1, deg_inv, h, N);
    aggregate128_kernel<<<(N + 7) / 8, 256, 0, stream>>>(se, sorted_src, (const unsigned*)h, b1,
                                                         (unsigned*)out1, N);
    gemm_mfma_kernel<64, 0><<<gblocks, 256, 0, stream>>>(out1, W2, deg_inv, g, N);
    aggregate64_kernel<<<(N + 7) / 8, 256, 0, stream>>>(se, sorted_src, (const unsigned*)g, b2, out, N);
}

// Round 7
// 319.383 us; speedup vs baseline: 13.8611x; 1.0306x over previous
//
#include <hip/hip_runtime.h>
#include <hip/hip_bf16.h>

// GCNEncoder: 2-layer GCN, out-degree norm. N=100000, E=1600000, 128->128->64, fp32 I/O.
// R7: GEMM 64-row M-tiles (52KB LDS -> 3 blocks/CU, 2x blocks: staging-latency bound fix);
// deg_inv folded into agg128 epilogue so layer-2 GEMM stages bf16 directly (no scale);
// aggregate unroll reverted to 4 (R5 config beat unroll-8); single cursor memset.
// agg128 FETCH ~177MB is structural: 8 XCDs x 86.5% x 25.6MB compulsory fills (measured match).

typedef __attribute__((ext_vector_type(8))) short short8;
typedef __attribute__((ext_vector_type(4))) float floatx4;

__device__ inline unsigned short f2bf(float f) {
    union { float f; unsigned u; } v; v.f = f;
    unsigned r = v.u + 0x7FFF + ((v.u >> 16) & 1);  // RNE
    return (unsigned short)(r >> 16);
}
__device__ inline float bf2f(unsigned short b) {
    union { unsigned u; float f; } v; v.u = ((unsigned)b) << 16;
    return v.f;
}

#define NBMAX 512   // max 256-node buckets -> N <= 131072 (src < 2^24 for packing)
#define CAP   8192  // fixed bucket capacity; mean 4092 for E=1.6M/NB=391; 64-sigma headroom

// ---- pass 1: LDS bucket histograms -> reserve runs via global cursors -> scatter ----
__global__ __launch_bounds__(256) void scatter2_kernel(
    const int* __restrict__ src, const int* __restrict__ dst, int E,
    int* __restrict__ cnt_d, int* __restrict__ cnt_s,   // stride-16 padded cursors
    unsigned* __restrict__ pairs, unsigned char* __restrict__ srcs_b, int NB)
{
    __shared__ int hd[NBMAX], bd[NBMAX], cd_[NBMAX];
    __shared__ int hs[NBMAX], bs[NBMAX], cs_[NBMAX];
    for (int i = threadIdx.x; i < NB; i += 256) { hd[i] = 0; cd_[i] = 0; hs[i] = 0; cs_[i] = 0; }
    __syncthreads();
    const int e0 = blockIdx.x * 8192;
    const int e1 = min(e0 + 8192, E);
    for (int i = e0 + threadIdx.x; i < e1; i += 256) {
        atomicAdd(&hd[dst[i] >> 8], 1);
        atomicAdd(&hs[src[i] >> 8], 1);
    }
    __syncthreads();
    for (int i = threadIdx.x; i < NB; i += 256) {
        if (hd[i]) bd[i] = atomicAdd(&cnt_d[i * 16], hd[i]);
        if (hs[i]) bs[i] = atomicAdd(&cnt_s[i * 16], hs[i]);
    }
    __syncthreads();
    for (int i = e0 + threadIdx.x; i < e1; i += 256) {
        int sv = src[i], dv = dst[i];
        int b = dv >> 8;
        int slot = atomicAdd(&cd_[b], 1);
        pairs[(size_t)b * CAP + bd[b] + slot] = ((unsigned)(dv & 255) << 24) | (unsigned)sv;
        int b2 = sv >> 8;
        int slot2 = atomicAdd(&cs_[b2], 1);
        srcs_b[(size_t)b2 * CAP + bs[b2] + slot2] = (unsigned char)(sv & 255);
    }
}

// ---- pass 2 (fused): per-bucket dst sort -> sorted_src + (start,end); src hist -> deg_inv ----
__global__ __launch_bounds__(256) void bucket_finalize_kernel(
    const unsigned* __restrict__ pairs, const unsigned char* __restrict__ srcs_b,
    const int* __restrict__ cnt_d, const int* __restrict__ cnt_s,
    int* __restrict__ sorted_src, int2* __restrict__ se,
    float* __restrict__ deg_inv, int N)
{
    const int b = blockIdx.x;
    const int node0 = b << 8;
    const int t = threadIdx.x;
    const size_t base = (size_t)b * CAP;
    __shared__ int hist[256];
    __shared__ int cur[256];
    __shared__ int pre[256];

    const int cd = cnt_d[b * 16];
    hist[t] = 0;
    __syncthreads();
    for (int i = t; i < cd; i += 256)
        atomicAdd(&hist[pairs[base + i] >> 24], 1);
    __syncthreads();
    int v = hist[t];
    pre[t] = v;
    __syncthreads();
    for (int o = 1; o < 256; o <<= 1) {
        int add = (t >= o) ? pre[t - o] : 0;
        __syncthreads();
        pre[t] += add;
        __syncthreads();
    }
    int excl = pre[t] - v;
    cur[t] = excl;
    if (node0 + t < N)
        se[node0 + t] = make_int2((int)base + excl, (int)base + excl + v);
    __syncthreads();
    for (int i = t; i < cd; i += 256) {
        unsigned p = pairs[base + i];
        int pos = atomicAdd(&cur[p >> 24], 1);
        sorted_src[base + pos] = (int)(p & 0xFFFFFFu);
    }

    __syncthreads();
    hist[t] = 0;
    __syncthreads();
    const int cs = cnt_s[b * 16];
    for (int i = t; i < cs; i += 256)
        atomicAdd(&hist[srcs_b[base + i]], 1);
    __syncthreads();
    if (node0 + t < N) {
        int d = hist[t];
        deg_inv[node0 + t] = 1.0f / (float)(d < 1 ? 1 : d);
    }
}

// ---------------- MFMA GEMM, 64-row M-tile ----------------
// AF=1: A fp32, scaled by deg_inv[row] during staging (layer 1).
// AF=0: A bf16 already scaled (layer 2) — pure copy staging.
template <int NC, int AF>
__global__ __launch_bounds__(256) void gemm_mfma_kernel(
    const void* __restrict__ Ap, const float* __restrict__ W,
    const float* __restrict__ scale, unsigned short* __restrict__ Cb, int M)
{
    __shared__ unsigned short Al[64][136];   // 17.4 KB
    __shared__ unsigned short Bl[NC][136];   // 34.8 / 17.4 KB

    const int t = threadIdx.x;
    const int r0 = blockIdx.x * 64;

    // stage A: 64 rows x 128 k
    for (int idx = t; idx < 64 * 32; idx += 256) {
        int r = idx >> 5, c4 = (idx & 31) << 2;
        int rg = r0 + r;
        ushort4 w;
        if (rg < M) {
            if (AF) {
                float s = scale[rg];
                float4 v = *(const float4*)&((const float*)Ap)[(size_t)rg * 128 + c4];
                w.x = f2bf(v.x * s); w.y = f2bf(v.y * s);
                w.z = f2bf(v.z * s); w.w = f2bf(v.w * s);
            } else {
                w = *(const ushort4*)&((const unsigned short*)Ap)[(size_t)rg * 128 + c4];
            }
        } else {
            w.x = w.y = w.z = w.w = 0;
        }
        *(ushort4*)&Al[r][c4] = w;
    }
    // stage W transposed: W[k][n] fp32 -> Bl[n][k] bf16
    for (int idx = t; idx < 128 * (NC / 4); idx += 256) {
        int k = idx / (NC / 4), n4 = (idx % (NC / 4)) << 2;
        float4 v = *(const float4*)&W[(size_t)k * NC + n4];
        Bl[n4 + 0][k] = f2bf(v.x);
        Bl[n4 + 1][k] = f2bf(v.y);
        Bl[n4 + 2][k] = f2bf(v.z);
        Bl[n4 + 3][k] = f2bf(v.w);
    }
    __syncthreads();

    constexpr int NT = NC / 16;
    const int wm = t >> 6;            // wave's 16-row band
    const int lane = t & 63;
    const int lm = lane & 15;
    const int lk = (lane >> 4) * 8;

    floatx4 acc[NT];
#pragma unroll
    for (int j = 0; j < NT; ++j) acc[j] = (floatx4){0.f, 0.f, 0.f, 0.f};

#pragma unroll
    for (int kk = 0; kk < 4; ++kk) {
        const int kb = kk * 32 + lk;
        short8 af = *(const short8*)&Al[wm * 16 + lm][kb];
#pragma unroll
        for (int j = 0; j < NT; ++j) {
            short8 bfr = *(const short8*)&Bl[j * 16 + lm][kb];
            acc[j] = __builtin_amdgcn_mfma_f32_16x16x32_bf16(af, bfr, acc[j], 0, 0, 0);
        }
    }

    const int rbase = r0 + wm * 16 + (lane >> 4) * 4;
#pragma unroll
    for (int reg = 0; reg < 4; ++reg) {
        int rg = rbase + reg;
        if (rg < M) {
#pragma unroll
            for (int j = 0; j < NT; ++j)
                Cb[(size_t)rg * NC + j * 16 + lm] = f2bf(acc[j][reg]);
        }
    }
}

// ---------------- aggregate C=128: half-wave/node, unroll 4; epilogue scales by deg_inv ----------------
__global__ __launch_bounds__(256) void aggregate128_kernel(
    const int2* __restrict__ se, const int* __restrict__ sorted_src,
    const unsigned* __restrict__ val, const float* __restrict__ bias,
    const float* __restrict__ deg_inv, unsigned* __restrict__ outb, int N)
{
    int node = blockIdx.x * 8 + (threadIdx.x >> 5);
    if (node >= N) return;
    int l = threadIdx.x & 31;
    int2 r = se[node];
    int e = r.x;
    const int end = r.y;
    float a0 = 0.f, a1 = 0.f, a2 = 0.f, a3 = 0.f;
    for (; e + 4 <= end; e += 4) {
        int s0 = sorted_src[e + 0], s1 = sorted_src[e + 1];
        int s2 = sorted_src[e + 2], s3 = sorted_src[e + 3];
        uint2 v0 = *(const uint2*)&val[(size_t)s0 * 64 + 2 * l];
        uint2 v1 = *(const uint2*)&val[(size_t)s1 * 64 + 2 * l];
        uint2 v2 = *(const uint2*)&val[(size_t)s2 * 64 + 2 * l];
        uint2 v3 = *(const uint2*)&val[(size_t)s3 * 64 + 2 * l];
        a0 += (bf2f(v0.x & 0xFFFF) + bf2f(v1.x & 0xFFFF)) + (bf2f(v2.x & 0xFFFF) + bf2f(v3.x & 0xFFFF));
        a1 += (bf2f(v0.x >> 16) + bf2f(v1.x >> 16)) + (bf2f(v2.x >> 16) + bf2f(v3.x >> 16));
        a2 += (bf2f(v0.y & 0xFFFF) + bf2f(v1.y & 0xFFFF)) + (bf2f(v2.y & 0xFFFF) + bf2f(v3.y & 0xFFFF));
        a3 += (bf2f(v0.y >> 16) + bf2f(v1.y >> 16)) + (bf2f(v2.y >> 16) + bf2f(v3.y >> 16));
    }
    for (; e < end; ++e) {
        uint2 v = *(const uint2*)&val[(size_t)sorted_src[e] * 64 + 2 * l];
        a0 += bf2f(v.x & 0xFFFF);
        a1 += bf2f(v.x >> 16);
        a2 += bf2f(v.y & 0xFFFF);
        a3 += bf2f(v.y >> 16);
    }
    float di = deg_inv[node];
    float4 bv = *(const float4*)&bias[4 * l];
    a0 = fmaxf(a0 + bv.x, 0.f) * di;
    a1 = fmaxf(a1 + bv.y, 0.f) * di;
    a2 = fmaxf(a2 + bv.z, 0.f) * di;
    a3 = fmaxf(a3 + bv.w, 0.f) * di;
    uint2 o;
    o.x = (unsigned)f2bf(a0) | ((unsigned)f2bf(a1) << 16);
    o.y = (unsigned)f2bf(a2) | ((unsigned)f2bf(a3) << 16);
    *(uint2*)&outb[(size_t)node * 64 + 2 * l] = o;
}

// ---------------- aggregate C=64 (bf16 in, fp32 out, +bias): half-wave/node, unroll 4 ----------------
__global__ __launch_bounds__(256) void aggregate64_kernel(
    const int2* __restrict__ se, const int* __restrict__ sorted_src,
    const unsigned* __restrict__ val, const float* __restrict__ bias,
    float* __restrict__ out, int N)
{
    int node = blockIdx.x * 8 + (threadIdx.x >> 5);
    if (node >= N) return;
    int l = threadIdx.x & 31;
    int2 r = se[node];
    int e = r.x;
    const int end = r.y;
    float ax = 0.f, ay = 0.f;
    for (; e + 4 <= end; e += 4) {
        int s0 = sorted_src[e + 0], s1 = sorted_src[e + 1];
        int s2 = sorted_src[e + 2], s3 = sorted_src[e + 3];
        unsigned v0 = val[(size_t)s0 * 32 + l];
        unsigned v1 = val[(size_t)s1 * 32 + l];
        unsigned v2 = val[(size_t)s2 * 32 + l];
        unsigned v3 = val[(size_t)s3 * 32 + l];
        ax += (bf2f(v0 & 0xFFFF) + bf2f(v1 & 0xFFFF)) + (bf2f(v2 & 0xFFFF) + bf2f(v3 & 0xFFFF));
        ay += (bf2f(v0 >> 16) + bf2f(v1 >> 16)) + (bf2f(v2 >> 16) + bf2f(v3 >> 16));
    }
    for (; e < end; ++e) {
        unsigned v = val[(size_t)sorted_src[e] * 32 + l];
        ax += bf2f(v & 0xFFFF);
        ay += bf2f(v >> 16);
    }
    float2 o = make_float2(ax + bias[2 * l], ay + bias[2 * l + 1]);
    *(float2*)&out[(size_t)node * 64 + 2 * l] = o;
}

extern "C" void kernel_launch(void* const* d_in, const int* in_sizes, int n_in,
                              void* d_out, int out_size, void* d_ws, size_t ws_size,
                              hipStream_t stream) {
    const float* x  = (const float*)d_in[0];
    const int*   ei = (const int*)d_in[1];
    const float* W1 = (const float*)d_in[2];
    const float* b1 = (const float*)d_in[3];
    const float* W2 = (const float*)d_in[4];
    const float* b2 = (const float*)d_in[5];
    float* out = (float*)d_out;

    const int N = in_sizes[0] / 128;
    const int E = in_sizes[1] / 2;
    const int* src = ei;
    const int* dst = ei + E;
    const int NB = (N + 255) >> 8;

    char* ws = (char*)d_ws;
    size_t off = 0;
    auto alloc = [&](size_t bytes) {
        void* p = ws + off;
        off = (off + bytes + 255) & ~(size_t)255;
        return p;
    };
    float* deg_inv  = (float*)alloc((size_t)N * 4);
    int2*  se       = (int2*)alloc((size_t)N * 8);
    int*   cnt_d    = (int*)alloc((size_t)NBMAX * 16 * 4 * 2);  // cnt_d | cnt_s adjacent
    int*   cnt_s    = cnt_d + (size_t)NBMAX * 16;
    unsigned*      pairs  = (unsigned*)alloc((size_t)NBMAX * CAP * 4);
    unsigned char* srcs_b = (unsigned char*)alloc((size_t)NBMAX * CAP);
    int*   sorted_src = (int*)alloc((size_t)NBMAX * CAP * 4);
    unsigned short* h    = (unsigned short*)alloc((size_t)N * 128 * 2);
    unsigned short* out1 = (unsigned short*)alloc((size_t)N * 128 * 2);
    unsigned short* g    = h;  // h dead after aggregate1

    hipMemsetAsync(cnt_d, 0, (size_t)NBMAX * 16 * 4 * 2, stream);

    scatter2_kernel<<<(E + 8191) / 8192, 256, 0, stream>>>(src, dst, E, cnt_d, cnt_s,
                                                           pairs, srcs_b, NB);
    bucket_finalize_kernel<<<NB, 256, 0, stream>>>(pairs, srcs_b, cnt_d, cnt_s,
                                                   sorted_src, se, deg_inv, N);

    const int gblocks = (N + 63) / 64;
    // layer 1: h = bf16((x*di) @ W1); out1 = bf16(relu(Agg(h)+b1) * di)
    gemm_mfma_kernel<128, 1><<<gblocks, 256, 0, stream>>>(x, W1, deg_inv, h, N);
    aggregate128_kernel<<<(N + 7) / 8, 256, 0, stream>>>(se, sorted_src, (const unsigned*)h, b1,
                                                         deg_inv, (unsigned*)out1, N);
    // layer 2: g = bf16(out1 @ W2); out = Agg(g) + b2
    gemm_mfma_kernel<64, 0><<<gblocks, 256, 0, stream>>>(out1, W2, deg_inv, g, N);
    aggregate64_kernel<<<(N + 7) / 8, 256, 0, stream>>>(se, sorted_src, (const unsigned*)g, b2, out, N);
}